// Round 1
// baseline (1380.755 us; speedup 1.0000x reference)
//
#include <hip/hip_runtime.h>
#include <math.h>

#define Bc 4
#define Lc 512
#define Dc 768
#define Hc 12
#define Mc 48
#define Ec 32
#define Pc 512
#define Rc 97
#define MINV 1e-30f

// ---------------- K1: mention[b,m,d] = sum_l mm[b,m,l] * context[b,l,d] ----------------
__global__ __launch_bounds__(256) void k_mention(const float* __restrict__ mm,
                                                 const float* __restrict__ ctx,
                                                 float* __restrict__ mention) {
    int bm = blockIdx.x; int b = bm / Mc;
    __shared__ float row[Lc];
    for (int l = threadIdx.x; l < Lc; l += 256) row[l] = mm[(size_t)bm * Lc + l];
    __syncthreads();
    for (int d = threadIdx.x; d < Dc; d += 256) {
        float acc = 0.f;
        const float* cb = ctx + (size_t)b * Lc * Dc + d;
        for (int l = 0; l < Lc; ++l) acc += row[l] * cb[(size_t)l * Dc];
        mention[(size_t)bm * Dc + d] = acc;
    }
}

// ---------------- K2: att_sum[b,i,j] = sum_h attention[b,h,i,j] ----------------
__global__ __launch_bounds__(256) void k_attsum(const float* __restrict__ att,
                                                float* __restrict__ as_) {
    int idx = blockIdx.x * 256 + threadIdx.x;
    if (idx >= Bc * Lc * Lc) return;
    int b = idx / (Lc * Lc); int rem = idx % (Lc * Lc);
    float acc = 0.f;
    const float* p = att + (size_t)b * Hc * Lc * Lc + rem;
    for (int h = 0; h < Hc; ++h) acc += p[(size_t)h * Lc * Lc];
    as_[idx] = acc;
}

// ---------------- K3a: tmpML[b,m,j] = sum_i mm[b,m,i] * att_sum[b,i,j] ----------------
__global__ __launch_bounds__(256) void k_mm_attsum(const float* __restrict__ mm,
                                                   const float* __restrict__ as_,
                                                   float* __restrict__ tmp) {
    int bm = blockIdx.x; int b = bm / Mc;
    __shared__ float row[Lc];
    for (int l = threadIdx.x; l < Lc; l += 256) row[l] = mm[(size_t)bm * Lc + l];
    __syncthreads();
    for (int j = threadIdx.x; j < Lc; j += 256) {
        float acc = 0.f;
        const float* ab = as_ + (size_t)b * Lc * Lc + j;
        for (int i = 0; i < Lc; ++i) acc += row[i] * ab[(size_t)i * Lc];
        tmp[(size_t)bm * Lc + j] = acc;
    }
}

// ---------------- K3b: mention_att[b,m,m2] = sum_j tmp[b,m,j]*mm[b,m2,j] ----------------
__global__ __launch_bounds__(256) void k_mention_att(const float* __restrict__ tmp,
                                                     const float* __restrict__ mm,
                                                     float* __restrict__ ma) {
    int idx = blockIdx.x * 256 + threadIdx.x;
    if (idx >= Bc * Mc * Mc) return;
    int b = idx / (Mc * Mc); int m = (idx / Mc) % Mc; int m2 = idx % Mc;
    float acc = 0.f;
    const float* t = tmp + (size_t)(b * Mc + m) * Lc;
    const float* r = mm + (size_t)(b * Mc + m2) * Lc;
    for (int j = 0; j < Lc; ++j) acc += t[j] * r[j];
    ma[idx] = acc;
}

// ---------------- K4: entity_att[b,e,m2] = sum_m em[b,e,m]*mention_att[b,m,m2] ----------------
__global__ __launch_bounds__(256) void k_entity_att(const float* __restrict__ em,
                                                    const float* __restrict__ ma,
                                                    float* __restrict__ ea) {
    int idx = blockIdx.x * 256 + threadIdx.x;
    if (idx >= Bc * Ec * Mc) return;
    int b = idx / (Ec * Mc); int e = (idx / Mc) % Ec; int m2 = idx % Mc;
    float acc = 0.f;
    const float* emr = em + (size_t)(b * Ec + e) * Mc;
    const float* mac = ma + (size_t)b * Mc * Mc + m2;
    for (int m = 0; m < Mc; ++m) acc += emr[m] * mac[(size_t)m * Mc];
    ea[idx] = acc;
}

// ---------------- K5: h_att/t_att normalize + h,t = att @ mention ----------------
__global__ __launch_bounds__(256) void k_ht(const int* __restrict__ hts,
                                            const float* __restrict__ em,
                                            const float* __restrict__ ea,
                                            const float* __restrict__ mention,
                                            float* __restrict__ hB, float* __restrict__ tB) {
    int bp = blockIdx.x; int b = bp / Pc;
    int hi = hts[bp * 2], ti = hts[bp * 2 + 1];
    float mask = (hi + ti != 0) ? 1.f : 0.f;
    __shared__ float hat[Mc], tat[Mc];
    __shared__ float sums[2];
    int tid = threadIdx.x;
    if (tid < Mc) {
        float hm = em[(size_t)(b * Ec + hi) * Mc + tid];
        float tm = em[(size_t)(b * Ec + ti) * Mc + tid];
        float eh = ea[(size_t)(b * Ec + hi) * Mc + tid];
        float et = ea[(size_t)(b * Ec + ti) * Mc + tid];
        hat[tid] = eh * tm * mask;   // h_att = entity_att[h_idx] * t_mask
        tat[tid] = et * hm * mask;   // t_att = entity_att[t_idx] * h_mask
    }
    __syncthreads();
    if (tid == 0) {
        float sh = 0.f, st = 0.f;
        for (int m = 0; m < Mc; ++m) { sh += hat[m]; st += tat[m]; }
        sums[0] = 1.f / (sh + MINV);
        sums[1] = 1.f / (st + MINV);
    }
    __syncthreads();
    float hnorm = sums[0], tnorm = sums[1];
    for (int d = tid; d < Dc; d += 256) {
        float ah = 0.f, at = 0.f;
        const float* mb = mention + (size_t)b * Mc * Dc + d;
        for (int m = 0; m < Mc; ++m) {
            float mv = mb[(size_t)m * Dc];
            ah += tat[m] * mv;   // h = t_att @ mention
            at += hat[m] * mv;   // t = h_att @ mention
        }
        hB[(size_t)bp * Dc + d] = ah * tnorm * mask;
        tB[(size_t)bp * Dc + d] = at * hnorm * mask;
    }
}

// ---------------- K6: em_tok[b,e,l] normalized ----------------
__global__ __launch_bounds__(256) void k_emtok(const float* __restrict__ em,
                                               const float* __restrict__ mm,
                                               float* __restrict__ emt) {
    int be = blockIdx.x; int b = be / Ec;
    __shared__ float row[Mc];
    __shared__ float red[256];
    __shared__ float inv;
    int tid = threadIdx.x;
    if (tid < Mc) row[tid] = em[(size_t)be * Mc + tid];
    __syncthreads();
    float v0 = 0.f, v1 = 0.f;
    {
        const float* mb0 = mm + (size_t)b * Mc * Lc + tid;
        const float* mb1 = mm + (size_t)b * Mc * Lc + tid + 256;
        for (int m = 0; m < Mc; ++m) {
            v0 += row[m] * mb0[(size_t)m * Lc];
            v1 += row[m] * mb1[(size_t)m * Lc];
        }
    }
    red[tid] = v0 + v1;
    __syncthreads();
    for (int s = 128; s > 0; s >>= 1) { if (tid < s) red[tid] += red[tid + s]; __syncthreads(); }
    if (tid == 0) inv = 1.f / (red[0] + MINV);
    __syncthreads();
    emt[(size_t)be * Lc + tid] = v0 * inv;
    emt[(size_t)be * Lc + tid + 256] = v1 * inv;
}

// ---------------- K7: ent_att[b,h,e,m] = sum_l em_tok[b,e,l]*att[b,h,l,m] ----------------
__global__ __launch_bounds__(256) void k_entatt(const float* __restrict__ emt,
                                                const float* __restrict__ att,
                                                float* __restrict__ eat) {
    int id = blockIdx.x; // b*H*E + h*E + e
    int b = id / (Hc * Ec); int h = (id / Ec) % Hc; int e = id % Ec;
    __shared__ float row[Lc];
    int tid = threadIdx.x;
    row[tid] = emt[(size_t)(b * Ec + e) * Lc + tid];
    row[tid + 256] = emt[(size_t)(b * Ec + e) * Lc + tid + 256];
    __syncthreads();
    float a0 = 0.f, a1 = 0.f;
    const float* ab = att + (size_t)(b * Hc + h) * Lc * Lc;
    for (int l = 0; l < Lc; ++l) {
        float ev = row[l];
        a0 += ev * ab[(size_t)l * Lc + tid];
        a1 += ev * ab[(size_t)l * Lc + tid + 256];
    }
    eat[(size_t)id * Lc + tid] = a0;
    eat[(size_t)id * Lc + tid + 256] = a1;
}

// ---------------- K8: ctx_att[b,p,l] = sum_h eat[b,h,hi,l]*eat[b,h,ti,l], normalized ----------------
__global__ __launch_bounds__(256) void k_ctxatt(const int* __restrict__ hts,
                                                const float* __restrict__ eat,
                                                float* __restrict__ ca) {
    int bp = blockIdx.x; int b = bp / Pc;
    int hi = hts[bp * 2], ti = hts[bp * 2 + 1];
    int tid = threadIdx.x;
    float a0 = 0.f, a1 = 0.f;
    for (int h = 0; h < Hc; ++h) {
        const float* ph = eat + ((size_t)(b * Hc + h) * Ec + hi) * Lc;
        const float* pt = eat + ((size_t)(b * Hc + h) * Ec + ti) * Lc;
        a0 += ph[tid] * pt[tid];
        a1 += ph[tid + 256] * pt[tid + 256];
    }
    __shared__ float red[256];
    __shared__ float inv;
    red[tid] = a0 + a1;
    __syncthreads();
    for (int s = 128; s > 0; s >>= 1) { if (tid < s) red[tid] += red[tid + s]; __syncthreads(); }
    if (tid == 0) inv = 1.f / (red[0] + MINV);
    __syncthreads();
    ca[(size_t)bp * Lc + tid] = a0 * inv;
    ca[(size_t)bp * Lc + tid + 256] = a1 * inv;
}

// ---------------- K9: context_info[b,p,d] = (ctx_att @ context) * mask ----------------
__global__ __launch_bounds__(256) void k_ctxinfo(const int* __restrict__ hts,
                                                 const float* __restrict__ ca,
                                                 const float* __restrict__ ctx,
                                                 float* __restrict__ ci) {
    int bt = blockIdx.x;
    int dt = bt % 3; int pt = (bt / 3) % (Pc / 8); int b = bt / (3 * (Pc / 8));
    int p0 = pt * 8;
    __shared__ float rows[8][Lc];
    __shared__ float masks[8];
    int tid = threadIdx.x;
    for (int idx = tid; idx < 8 * Lc; idx += 256) {
        int k = idx / Lc, l = idx % Lc;
        rows[k][l] = ca[(size_t)(b * Pc + p0 + k) * Lc + l];
    }
    if (tid < 8) {
        int bp = b * Pc + p0 + tid;
        masks[tid] = (hts[bp * 2] + hts[bp * 2 + 1] != 0) ? 1.f : 0.f;
    }
    __syncthreads();
    int d = dt * 256 + tid;
    float acc[8] = {0.f, 0.f, 0.f, 0.f, 0.f, 0.f, 0.f, 0.f};
    const float* cb = ctx + (size_t)b * Lc * Dc + d;
    for (int l = 0; l < Lc; ++l) {
        float cv = cb[(size_t)l * Dc];
#pragma unroll
        for (int k = 0; k < 8; ++k) acc[k] += rows[k][l] * cv;
    }
#pragma unroll
    for (int k = 0; k < 8; ++k)
        ci[(size_t)(b * Pc + p0 + k) * Dc + d] = acc[k] * masks[k];
}

// ---------------- K10: out = tanh(X1@W1^T + b1 + X2@W2^T + b2) ----------------
// M=2048, N=768, K=768. BM=BN=64, BK=16, 256 threads, 4x4 micro-tile.
__global__ __launch_bounds__(256) void k_proj(const float* __restrict__ X1, const float* __restrict__ W1,
                                              const float* __restrict__ b1,
                                              const float* __restrict__ X2, const float* __restrict__ W2,
                                              const float* __restrict__ b2,
                                              float* __restrict__ out) {
    __shared__ float Xs[16][64];
    __shared__ float Ws[16][64];
    int bm = blockIdx.x; // 0..31
    int bn = blockIdx.y; // 0..11
    int tid = threadIdx.x;
    int tn = tid % 16, tm = tid / 16;
    float acc[4][4] = {};
    int lrow = tid / 4;          // 0..63
    int lcol = (tid % 4) * 4;    // 0,4,8,12
    for (int src = 0; src < 2; ++src) {
        const float* X = src ? X2 : X1;
        const float* W = src ? W2 : W1;
        for (int k0 = 0; k0 < Dc; k0 += 16) {
            float4 xv = *(const float4*)&X[(size_t)(bm * 64 + lrow) * Dc + k0 + lcol];
            float4 wv = *(const float4*)&W[(size_t)(bn * 64 + lrow) * Dc + k0 + lcol];
            __syncthreads();
            Xs[lcol][lrow] = xv.x; Xs[lcol + 1][lrow] = xv.y; Xs[lcol + 2][lrow] = xv.z; Xs[lcol + 3][lrow] = xv.w;
            Ws[lcol][lrow] = wv.x; Ws[lcol + 1][lrow] = wv.y; Ws[lcol + 2][lrow] = wv.z; Ws[lcol + 3][lrow] = wv.w;
            __syncthreads();
#pragma unroll
            for (int k = 0; k < 16; ++k) {
                float4 a = *(const float4*)&Xs[k][tm * 4];
                float4 bv = *(const float4*)&Ws[k][tn * 4];
                acc[0][0] += a.x * bv.x; acc[0][1] += a.x * bv.y; acc[0][2] += a.x * bv.z; acc[0][3] += a.x * bv.w;
                acc[1][0] += a.y * bv.x; acc[1][1] += a.y * bv.y; acc[1][2] += a.y * bv.z; acc[1][3] += a.y * bv.w;
                acc[2][0] += a.z * bv.x; acc[2][1] += a.z * bv.y; acc[2][2] += a.z * bv.z; acc[2][3] += a.z * bv.w;
                acc[3][0] += a.w * bv.x; acc[3][1] += a.w * bv.y; acc[3][2] += a.w * bv.z; acc[3][3] += a.w * bv.w;
            }
        }
    }
#pragma unroll
    for (int i = 0; i < 4; ++i) {
        int m = bm * 64 + tm * 4 + i;
#pragma unroll
        for (int j = 0; j < 4; ++j) {
            int n = bn * 64 + tn * 4 + j;
            out[(size_t)m * Dc + n] = tanhf(acc[i][j] + b1[n] + b2[n]);
        }
    }
}

// ---------------- K11a: init out with bias ----------------
__global__ __launch_bounds__(256) void k_outinit(const float* __restrict__ cb, float* __restrict__ out) {
    int idx = blockIdx.x * 256 + threadIdx.x;
    if (idx < Bc * Pc * Rc) out[idx] = cb[idx % Rc];
}

// ---------------- K11b: group bilinear, out[bp,r] += sum_{i,j} h[n,i] t[n,j] W[r,n,i,j] ----------------
__global__ __launch_bounds__(256) void k_bilin(const float* __restrict__ hF, const float* __restrict__ tF,
                                               const float* __restrict__ cw, float* __restrict__ out) {
    int bpt = blockIdx.x;  // 0..31
    int n = blockIdx.y;    // 0..11
    int bp0 = bpt * 64;
    __shared__ float hs[64][64];    // [bp][i]
    __shared__ float tsT[64][64];   // [j][bp]
    __shared__ float Wl[64][104];   // [j][r], padded
    int tid = threadIdx.x;
    for (int idx = tid; idx < 64 * 64; idx += 256) {
        int bp = idx / 64, x = idx % 64;
        float hv = hF[(size_t)(bp0 + bp) * Dc + n * 64 + x];
        float tv = tF[(size_t)(bp0 + bp) * Dc + n * 64 + x];
        hs[bp][x] = hv;
        tsT[x][bp] = tv;
    }
    int bg = tid % 16;  // bp group of 4
    int rg = tid / 16;  // 0..15
    float acc[4][7] = {};
    for (int i = 0; i < 64; ++i) {
        __syncthreads();
        const float* wb = cw + (size_t)n * 4096 + (size_t)i * 64;
        for (int idx = tid; idx < Rc * 64; idx += 256) {
            int r = idx / 64, j = idx % 64;
            Wl[j][r] = wb[(size_t)r * (Dc * 64) + j];
        }
        __syncthreads();
        float hv[4];
#pragma unroll
        for (int kk = 0; kk < 4; ++kk) hv[kk] = hs[bg * 4 + kk][i];
        for (int j = 0; j < 64; ++j) {
            float4 t4 = *(const float4*)&tsT[j][bg * 4];
            float a0 = hv[0] * t4.x, a1 = hv[1] * t4.y, a2 = hv[2] * t4.z, a3 = hv[3] * t4.w;
#pragma unroll
            for (int rr = 0; rr < 6; ++rr) {
                float w = Wl[j][rg + rr * 16];
                acc[0][rr] += a0 * w; acc[1][rr] += a1 * w; acc[2][rr] += a2 * w; acc[3][rr] += a3 * w;
            }
            if (rg == 0) {
                float w = Wl[j][96];
                acc[0][6] += a0 * w; acc[1][6] += a1 * w; acc[2][6] += a2 * w; acc[3][6] += a3 * w;
            }
        }
    }
    int nr = (rg == 0) ? 7 : 6;
    for (int kk = 0; kk < 4; ++kk)
        for (int rr = 0; rr < nr; ++rr) {
            int r = rg + rr * 16;
            atomicAdd(&out[(size_t)(bp0 + bg * 4 + kk) * Rc + r], acc[kk][rr]);
        }
}

extern "C" void kernel_launch(void* const* d_in, const int* in_sizes, int n_in,
                              void* d_out, int out_size, void* d_ws, size_t ws_size,
                              hipStream_t stream) {
    const float* context   = (const float*)d_in[0];
    const float* attention = (const float*)d_in[1];
    const float* mm        = (const float*)d_in[2];
    const float* em        = (const float*)d_in[3];
    const int*   hts       = (const int*)d_in[4];
    const float* hW        = (const float*)d_in[5];
    const float* hb        = (const float*)d_in[6];
    const float* tW        = (const float*)d_in[7];
    const float* tb        = (const float*)d_in[8];
    const float* hcW       = (const float*)d_in[9];
    const float* hcb       = (const float*)d_in[10];
    const float* tcW       = (const float*)d_in[11];
    const float* tcb       = (const float*)d_in[12];
    const float* clasW     = (const float*)d_in[13];
    const float* clasb     = (const float*)d_in[14];
    float* out = (float*)d_out;

    float* ws = (float*)d_ws;
    size_t off = 0;
    float* mention     = ws + off; off += (size_t)Bc * Mc * Dc;       // 147456
    float* att_sum     = ws + off; off += (size_t)Bc * Lc * Lc;       // 1048576
    float* tmpML       = ws + off; off += (size_t)Bc * Mc * Lc;       // 98304
    float* mention_att = ws + off; off += (size_t)Bc * Mc * Mc;       // 9216
    float* entity_att  = ws + off; off += (size_t)Bc * Ec * Mc;       // 6144
    float* h_buf       = ws + off; off += (size_t)Bc * Pc * Dc;       // 1572864
    float* t_buf       = ws + off; off += (size_t)Bc * Pc * Dc;
    float* em_tok      = ws + off; off += (size_t)Bc * Ec * Lc;       // 65536
    float* ent_att     = ws + off; off += (size_t)Bc * Hc * Ec * Lc;  // 786432
    float* ctx_att     = ws + off; off += (size_t)Bc * Pc * Lc;       // 1048576
    float* ctx_info    = ws + off; off += (size_t)Bc * Pc * Dc;
    float* h_fin       = ws + off; off += (size_t)Bc * Pc * Dc;
    float* t_fin       = ws + off; off += (size_t)Bc * Pc * Dc;

    k_attsum<<<dim3((Bc * Lc * Lc + 255) / 256), dim3(256), 0, stream>>>(attention, att_sum);
    k_mention<<<dim3(Bc * Mc), dim3(256), 0, stream>>>(mm, context, mention);
    k_mm_attsum<<<dim3(Bc * Mc), dim3(256), 0, stream>>>(mm, att_sum, tmpML);
    k_mention_att<<<dim3((Bc * Mc * Mc + 255) / 256), dim3(256), 0, stream>>>(tmpML, mm, mention_att);
    k_entity_att<<<dim3((Bc * Ec * Mc + 255) / 256), dim3(256), 0, stream>>>(em, mention_att, entity_att);
    k_ht<<<dim3(Bc * Pc), dim3(256), 0, stream>>>(hts, em, entity_att, mention, h_buf, t_buf);
    k_emtok<<<dim3(Bc * Ec), dim3(256), 0, stream>>>(em, mm, em_tok);
    k_entatt<<<dim3(Bc * Hc * Ec), dim3(256), 0, stream>>>(em_tok, attention, ent_att);
    k_ctxatt<<<dim3(Bc * Pc), dim3(256), 0, stream>>>(hts, ent_att, ctx_att);
    k_ctxinfo<<<dim3(Bc * (Pc / 8) * 3), dim3(256), 0, stream>>>(hts, ctx_att, context, ctx_info);
    k_proj<<<dim3(32, 12), dim3(256), 0, stream>>>(h_buf, hW, hb, ctx_info, hcW, hcb, h_fin);
    k_proj<<<dim3(32, 12), dim3(256), 0, stream>>>(t_buf, tW, tb, ctx_info, tcW, tcb, t_fin);
    k_outinit<<<dim3((Bc * Pc * Rc + 255) / 256), dim3(256), 0, stream>>>(clasb, out);
    k_bilin<<<dim3(32, 12), dim3(256), 0, stream>>>(h_fin, t_fin, clasW, out);
}

// Round 2
// 594.657 us; speedup vs baseline: 2.3219x; 2.3219x over previous
//
#include <hip/hip_runtime.h>
#include <math.h>

#define Bc 4
#define Lc 512
#define Dc 768
#define Hc 12
#define Mc 48
#define Ec 32
#define Pc 512
#define Rc 97
#define MINV 1e-30f

typedef __bf16 bf16;
typedef __attribute__((ext_vector_type(8))) __bf16 bf16x8;
typedef __attribute__((ext_vector_type(4))) __bf16 bf16x4;
typedef __attribute__((ext_vector_type(16))) float f32x16;

// ---------------- K0: fp32 -> bf16 convert ----------------
__global__ __launch_bounds__(256) void k_cvt(const float* __restrict__ s, bf16* __restrict__ d, int nElem) {
    int i = blockIdx.x * 256 + threadIdx.x;
    int stride = gridDim.x * 256;
    for (; i < nElem; i += stride) d[i] = (bf16)s[i];
}

// ---------------- K1: mention[b,m,d] = sum_l mm[b,m,l] * context[b,l,d] ----------------
__global__ __launch_bounds__(256) void k_mention(const float* __restrict__ mm,
                                                 const float* __restrict__ ctx,
                                                 float* __restrict__ mention) {
    int bm = blockIdx.x; int b = bm / Mc;
    __shared__ float row[Lc];
    for (int l = threadIdx.x; l < Lc; l += 256) row[l] = mm[(size_t)bm * Lc + l];
    __syncthreads();
    for (int d = threadIdx.x; d < Dc; d += 256) {
        float acc = 0.f;
        const float* cb = ctx + (size_t)b * Lc * Dc + d;
        for (int l = 0; l < Lc; ++l) acc += row[l] * cb[(size_t)l * Dc];
        mention[(size_t)bm * Dc + d] = acc;
    }
}

// ---------------- K2: att_sum[b,i,j] = sum_h attention[b,h,i,j] ----------------
__global__ __launch_bounds__(256) void k_attsum(const float* __restrict__ att,
                                                float* __restrict__ as_) {
    int idx = blockIdx.x * 256 + threadIdx.x;
    if (idx >= Bc * Lc * Lc) return;
    int b = idx / (Lc * Lc); int rem = idx % (Lc * Lc);
    float acc = 0.f;
    const float* p = att + (size_t)b * Hc * Lc * Lc + rem;
    for (int h = 0; h < Hc; ++h) acc += p[(size_t)h * Lc * Lc];
    as_[idx] = acc;
}

// ---------------- K3a: tmpML[b,m,j] = sum_i mm[b,m,i] * att_sum[b,i,j] ----------------
__global__ __launch_bounds__(256) void k_mm_attsum(const float* __restrict__ mm,
                                                   const float* __restrict__ as_,
                                                   float* __restrict__ tmp) {
    int bm = blockIdx.x; int b = bm / Mc;
    __shared__ float row[Lc];
    for (int l = threadIdx.x; l < Lc; l += 256) row[l] = mm[(size_t)bm * Lc + l];
    __syncthreads();
    for (int j = threadIdx.x; j < Lc; j += 256) {
        float acc = 0.f;
        const float* ab = as_ + (size_t)b * Lc * Lc + j;
        for (int i = 0; i < Lc; ++i) acc += row[i] * ab[(size_t)i * Lc];
        tmp[(size_t)bm * Lc + j] = acc;
    }
}

// ---------------- K3b: mention_att[b,m,m2] = sum_j tmp[b,m,j]*mm[b,m2,j] ----------------
__global__ __launch_bounds__(256) void k_mention_att(const float* __restrict__ tmp,
                                                     const float* __restrict__ mm,
                                                     float* __restrict__ ma) {
    int idx = blockIdx.x * 256 + threadIdx.x;
    if (idx >= Bc * Mc * Mc) return;
    int b = idx / (Mc * Mc); int m = (idx / Mc) % Mc; int m2 = idx % Mc;
    float acc = 0.f;
    const float* t = tmp + (size_t)(b * Mc + m) * Lc;
    const float* r = mm + (size_t)(b * Mc + m2) * Lc;
    for (int j = 0; j < Lc; ++j) acc += t[j] * r[j];
    ma[idx] = acc;
}

// ---------------- K4: entity_att[b,e,m2] = sum_m em[b,e,m]*mention_att[b,m,m2] ----------------
__global__ __launch_bounds__(256) void k_entity_att(const float* __restrict__ em,
                                                    const float* __restrict__ ma,
                                                    float* __restrict__ ea) {
    int idx = blockIdx.x * 256 + threadIdx.x;
    if (idx >= Bc * Ec * Mc) return;
    int b = idx / (Ec * Mc); int e = (idx / Mc) % Ec; int m2 = idx % Mc;
    float acc = 0.f;
    const float* emr = em + (size_t)(b * Ec + e) * Mc;
    const float* mac = ma + (size_t)b * Mc * Mc + m2;
    for (int m = 0; m < Mc; ++m) acc += emr[m] * mac[(size_t)m * Mc];
    ea[idx] = acc;
}

// ---------------- K5: h_att/t_att normalize + h,t = att @ mention (bf16 out) ----------------
__global__ __launch_bounds__(256) void k_ht(const int* __restrict__ hts,
                                            const float* __restrict__ em,
                                            const float* __restrict__ ea,
                                            const float* __restrict__ mention,
                                            bf16* __restrict__ hB, bf16* __restrict__ tB) {
    int bp = blockIdx.x; int b = bp / Pc;
    int hi = hts[bp * 2], ti = hts[bp * 2 + 1];
    float mask = (hi + ti != 0) ? 1.f : 0.f;
    __shared__ float hat[Mc], tat[Mc];
    __shared__ float sums[2];
    int tid = threadIdx.x;
    if (tid < Mc) {
        float hm = em[(size_t)(b * Ec + hi) * Mc + tid];
        float tm = em[(size_t)(b * Ec + ti) * Mc + tid];
        float eh = ea[(size_t)(b * Ec + hi) * Mc + tid];
        float et = ea[(size_t)(b * Ec + ti) * Mc + tid];
        hat[tid] = eh * tm * mask;   // h_att = entity_att[h_idx] * t_mask
        tat[tid] = et * hm * mask;   // t_att = entity_att[t_idx] * h_mask
    }
    __syncthreads();
    if (tid == 0) {
        float sh = 0.f, st = 0.f;
        for (int m = 0; m < Mc; ++m) { sh += hat[m]; st += tat[m]; }
        sums[0] = 1.f / (sh + MINV);
        sums[1] = 1.f / (st + MINV);
    }
    __syncthreads();
    float hnorm = sums[0], tnorm = sums[1];
    for (int d = tid; d < Dc; d += 256) {
        float ah = 0.f, at = 0.f;
        const float* mb = mention + (size_t)b * Mc * Dc + d;
        for (int m = 0; m < Mc; ++m) {
            float mv = mb[(size_t)m * Dc];
            ah += tat[m] * mv;   // h = t_att @ mention
            at += hat[m] * mv;   // t = h_att @ mention
        }
        hB[(size_t)bp * Dc + d] = (bf16)(ah * tnorm * mask);
        tB[(size_t)bp * Dc + d] = (bf16)(at * hnorm * mask);
    }
}

// ---------------- K6: em_tok[b,e,l] normalized ----------------
__global__ __launch_bounds__(256) void k_emtok(const float* __restrict__ em,
                                               const float* __restrict__ mm,
                                               float* __restrict__ emt) {
    int be = blockIdx.x; int b = be / Ec;
    __shared__ float row[Mc];
    __shared__ float red[256];
    __shared__ float inv;
    int tid = threadIdx.x;
    if (tid < Mc) row[tid] = em[(size_t)be * Mc + tid];
    __syncthreads();
    float v0 = 0.f, v1 = 0.f;
    {
        const float* mb0 = mm + (size_t)b * Mc * Lc + tid;
        const float* mb1 = mm + (size_t)b * Mc * Lc + tid + 256;
        for (int m = 0; m < Mc; ++m) {
            v0 += row[m] * mb0[(size_t)m * Lc];
            v1 += row[m] * mb1[(size_t)m * Lc];
        }
    }
    red[tid] = v0 + v1;
    __syncthreads();
    for (int s = 128; s > 0; s >>= 1) { if (tid < s) red[tid] += red[tid + s]; __syncthreads(); }
    if (tid == 0) inv = 1.f / (red[0] + MINV);
    __syncthreads();
    emt[(size_t)be * Lc + tid] = v0 * inv;
    emt[(size_t)be * Lc + tid + 256] = v1 * inv;
}

// ---------------- K7: ent_att[b,h,e,m] = sum_l em_tok[b,e,l]*att[b,h,l,m] ----------------
__global__ __launch_bounds__(256) void k_entatt(const float* __restrict__ emt,
                                                const float* __restrict__ att,
                                                float* __restrict__ eat) {
    int id = blockIdx.x; // b*H*E + h*E + e
    int b = id / (Hc * Ec); int h = (id / Ec) % Hc; int e = id % Ec;
    __shared__ float row[Lc];
    int tid = threadIdx.x;
    row[tid] = emt[(size_t)(b * Ec + e) * Lc + tid];
    row[tid + 256] = emt[(size_t)(b * Ec + e) * Lc + tid + 256];
    __syncthreads();
    float a0 = 0.f, a1 = 0.f;
    const float* ab = att + (size_t)(b * Hc + h) * Lc * Lc;
    for (int l = 0; l < Lc; ++l) {
        float ev = row[l];
        a0 += ev * ab[(size_t)l * Lc + tid];
        a1 += ev * ab[(size_t)l * Lc + tid + 256];
    }
    eat[(size_t)id * Lc + tid] = a0;
    eat[(size_t)id * Lc + tid + 256] = a1;
}

// ---------------- K8: ctx_att[b,p,l] = sum_h eat[b,h,hi,l]*eat[b,h,ti,l], normalized ----------------
__global__ __launch_bounds__(256) void k_ctxatt(const int* __restrict__ hts,
                                                const float* __restrict__ eat,
                                                float* __restrict__ ca) {
    int bp = blockIdx.x; int b = bp / Pc;
    int hi = hts[bp * 2], ti = hts[bp * 2 + 1];
    int tid = threadIdx.x;
    float a0 = 0.f, a1 = 0.f;
    for (int h = 0; h < Hc; ++h) {
        const float* ph = eat + ((size_t)(b * Hc + h) * Ec + hi) * Lc;
        const float* pt = eat + ((size_t)(b * Hc + h) * Ec + ti) * Lc;
        a0 += ph[tid] * pt[tid];
        a1 += ph[tid + 256] * pt[tid + 256];
    }
    __shared__ float red[256];
    __shared__ float inv;
    red[tid] = a0 + a1;
    __syncthreads();
    for (int s = 128; s > 0; s >>= 1) { if (tid < s) red[tid] += red[tid + s]; __syncthreads(); }
    if (tid == 0) inv = 1.f / (red[0] + MINV);
    __syncthreads();
    ca[(size_t)bp * Lc + tid] = a0 * inv;
    ca[(size_t)bp * Lc + tid + 256] = a1 * inv;
}

// ---------------- K9: context_info[b,p,d] = (ctx_att @ context) * mask (bf16 out) ----------------
__global__ __launch_bounds__(256) void k_ctxinfo(const int* __restrict__ hts,
                                                 const float* __restrict__ ca,
                                                 const float* __restrict__ ctx,
                                                 bf16* __restrict__ ci) {
    int bt = blockIdx.x;
    int dt = bt % 3; int pt = (bt / 3) % (Pc / 8); int b = bt / (3 * (Pc / 8));
    int p0 = pt * 8;
    __shared__ float rows[8][Lc];
    __shared__ float masks[8];
    int tid = threadIdx.x;
    for (int idx = tid; idx < 8 * Lc; idx += 256) {
        int k = idx / Lc, l = idx % Lc;
        rows[k][l] = ca[(size_t)(b * Pc + p0 + k) * Lc + l];
    }
    if (tid < 8) {
        int bp = b * Pc + p0 + tid;
        masks[tid] = (hts[bp * 2] + hts[bp * 2 + 1] != 0) ? 1.f : 0.f;
    }
    __syncthreads();
    int d = dt * 256 + tid;
    float acc[8] = {0.f, 0.f, 0.f, 0.f, 0.f, 0.f, 0.f, 0.f};
    const float* cb = ctx + (size_t)b * Lc * Dc + d;
    for (int l = 0; l < Lc; ++l) {
        float cv = cb[(size_t)l * Dc];
#pragma unroll
        for (int k = 0; k < 8; ++k) acc[k] += rows[k][l] * cv;
    }
#pragma unroll
    for (int k = 0; k < 8; ++k)
        ci[(size_t)(b * Pc + p0 + k) * Dc + d] = (bf16)(acc[k] * masks[k]);
}

// ---------------- K10: MFMA proj: out = tanh(X1@W1^T + X2@W2^T + b1 + b2), bf16 out ----------------
// M=2048, N=768, K=768 x2 sources. Block 64x64, 4 waves of 32x32 mfma_32x32x16_bf16.
__global__ __launch_bounds__(256) void k_proj_mfma(const bf16* __restrict__ X1, const bf16* __restrict__ W1,
                                                   const float* __restrict__ b1,
                                                   const bf16* __restrict__ X2, const bf16* __restrict__ W2,
                                                   const float* __restrict__ b2,
                                                   bf16* __restrict__ outp) {
    __shared__ __align__(16) bf16 Xs[64 * 64];
    __shared__ __align__(16) bf16 Ws[64 * 64];
    int m0 = blockIdx.x * 64, n0 = blockIdx.y * 64;
    int tid = threadIdx.x;
    int w = tid >> 6, lane = tid & 63;
    int w_m = w & 1, w_n = w >> 1;
    int m_l = lane & 31, kg = lane >> 5;
    const bf16* Xarr[2] = {X1, X2};
    const bf16* Warr[2] = {W1, W2};
    int r0 = tid >> 3, c0 = tid & 7;       // chunk coords: r 0..31, c 0..7
    int r1 = r0 + 32;
    bf16x8 xr0, xr1, wr0, wr1;
    {
        const bf16* X = Xarr[0]; const bf16* W = Warr[0];
        xr0 = *(const bf16x8*)(X + (size_t)(m0 + r0) * Dc + c0 * 8);
        xr1 = *(const bf16x8*)(X + (size_t)(m0 + r1) * Dc + c0 * 8);
        wr0 = *(const bf16x8*)(W + (size_t)(n0 + r0) * Dc + c0 * 8);
        wr1 = *(const bf16x8*)(W + (size_t)(n0 + r1) * Dc + c0 * 8);
    }
    f32x16 acc;
#pragma unroll
    for (int i = 0; i < 16; ++i) acc[i] = 0.f;
    int ar = w_m * 32 + m_l;
    int br = w_n * 32 + m_l;
    for (int it = 0; it < 24; ++it) {
        __syncthreads();
        ((bf16x8*)Xs)[r0 * 8 + (c0 ^ (r0 & 7))] = xr0;
        ((bf16x8*)Xs)[r1 * 8 + (c0 ^ (r1 & 7))] = xr1;
        ((bf16x8*)Ws)[r0 * 8 + (c0 ^ (r0 & 7))] = wr0;
        ((bf16x8*)Ws)[r1 * 8 + (c0 ^ (r1 & 7))] = wr1;
        __syncthreads();
        if (it < 23) {
            int nxt = it + 1;
            int src = nxt / 12; int k0 = (nxt % 12) * 64;
            const bf16* X = Xarr[src]; const bf16* W = Warr[src];
            xr0 = *(const bf16x8*)(X + (size_t)(m0 + r0) * Dc + k0 + c0 * 8);
            xr1 = *(const bf16x8*)(X + (size_t)(m0 + r1) * Dc + k0 + c0 * 8);
            wr0 = *(const bf16x8*)(W + (size_t)(n0 + r0) * Dc + k0 + c0 * 8);
            wr1 = *(const bf16x8*)(W + (size_t)(n0 + r1) * Dc + k0 + c0 * 8);
        }
#pragma unroll
        for (int s = 0; s < 4; ++s) {
            int ck = s * 2 + kg;
            bf16x8 a = ((const bf16x8*)Xs)[ar * 8 + (ck ^ (ar & 7))];
            bf16x8 b = ((const bf16x8*)Ws)[br * 8 + (ck ^ (br & 7))];
            acc = __builtin_amdgcn_mfma_f32_32x32x16_bf16(a, b, acc, 0, 0, 0);
        }
    }
#pragma unroll
    for (int reg = 0; reg < 16; ++reg) {
        int row = (reg & 3) + 8 * (reg >> 2) + 4 * kg;
        int m = m0 + w_m * 32 + row;
        int n = n0 + w_n * 32 + m_l;
        float v = tanhf(acc[reg] + b1[n] + b2[n]);
        outp[(size_t)m * Dc + n] = (bf16)v;
    }
}

// ---------------- K11a: init out with bias ----------------
__global__ __launch_bounds__(256) void k_outinit(const float* __restrict__ cb, float* __restrict__ out) {
    int idx = blockIdx.x * 256 + threadIdx.x;
    if (idx < Bc * Pc * Rc) out[idx] = cb[idx % Rc];
}

// ---------------- K11b: MFMA group bilinear ----------------
// out[bp,r] += sum_k feat[bp,k] W[r,k], k = n*4096 + i*64 + j, feat = h[bp,n*64+i]*t[bp,n*64+j].
// Grid (32 bp-tiles, 12 n). Block: 64 bp x 128 r(97 padded). 4 waves: w_m = bp half, w_n = r half (2 tiles of 32).
__global__ __launch_bounds__(256) void k_bilin_mfma(const bf16* __restrict__ hF, const bf16* __restrict__ tF,
                                                    const bf16* __restrict__ Wb, float* __restrict__ outp) {
    __shared__ float hs[64 * 65];                 // h[bp][i] fp32, pad 65 -> conflict-free per-iter scalar read
    __shared__ float4 ts4[64 * 16];               // t[bp] as 16 float4 chunks, XOR-swizzled by bp
    __shared__ __align__(16) bf16 Wl[128 * 64];   // W tile [r][k], 16B chunks XOR-swizzled by r
    int bp0 = blockIdx.x * 64;
    int n = blockIdx.y;
    int tid = threadIdx.x;
    int w = tid >> 6, lane = tid & 63;
    int w_m = w & 1, w_n = w >> 1;
    int m_l = lane & 31, kg = lane >> 5;

    // zero-fill Wl (rows 97..127 stay zero forever)
    for (int idx = tid; idx < 1024; idx += 256) ((float4*)Wl)[idx] = make_float4(0.f, 0.f, 0.f, 0.f);
    // stage h (fp32)
    for (int idx = tid; idx < 4096; idx += 256) {
        int bp = idx >> 6, i = idx & 63;
        hs[bp * 65 + i] = (float)hF[(size_t)(bp0 + bp) * Dc + n * 64 + i];
    }
    // stage t (fp32, swizzled float4 chunks)
    for (int idx = tid; idx < 1024; idx += 256) {
        int bp = idx >> 4, c = idx & 15;
        bf16x4 tv = *(const bf16x4*)(tF + (size_t)(bp0 + bp) * Dc + n * 64 + c * 4);
        float4 f;
        f.x = (float)tv[0]; f.y = (float)tv[1]; f.z = (float)tv[2]; f.w = (float)tv[3];
        ts4[bp * 16 + (c ^ (bp & 15))] = f;
    }
    // W prefetch registers: 97 rows x 8 chunks = 776 chunks, 4 per thread
    const bf16* wbase = Wb + (size_t)n * 4096;
    int wr_[4], wc_[4]; bool wv_[4];
    bf16x8 wreg[4];
#pragma unroll
    for (int p = 0; p < 4; ++p) {
        int idx = tid + p * 256;
        wv_[p] = idx < Rc * 8;
        wr_[p] = idx >> 3; wc_[p] = idx & 7;
    }
#pragma unroll
    for (int p = 0; p < 4; ++p)
        if (wv_[p]) wreg[p] = *(const bf16x8*)(wbase + (size_t)wr_[p] * (Dc * 64) + wc_[p] * 8);

    f32x16 acc0, acc1;
#pragma unroll
    for (int i = 0; i < 16; ++i) { acc0[i] = 0.f; acc1[i] = 0.f; }

    int bp_l = w_m * 32 + m_l;
    int rr0 = w_n * 64 + m_l;
    int rr1 = rr0 + 32;
    for (int iter = 0; iter < 64; ++iter) {
        __syncthreads();
#pragma unroll
        for (int p = 0; p < 4; ++p)
            if (wv_[p]) ((bf16x8*)Wl)[wr_[p] * 8 + (wc_[p] ^ (wr_[p] & 7))] = wreg[p];
        __syncthreads();
        if (iter < 63) {
#pragma unroll
            for (int p = 0; p < 4; ++p)
                if (wv_[p]) wreg[p] = *(const bf16x8*)(wbase + (size_t)wr_[p] * (Dc * 64) + (iter + 1) * 64 + wc_[p] * 8);
        }
        float hv = hs[bp_l * 65 + iter];
#pragma unroll
        for (int s = 0; s < 4; ++s) {
            int c0 = s * 4 + kg * 2;
            float4 t0 = ts4[bp_l * 16 + (c0 ^ (bp_l & 15))];
            float4 t1 = ts4[bp_l * 16 + ((c0 + 1) ^ (bp_l & 15))];
            bf16x8 a;
            a[0] = (bf16)(hv * t0.x); a[1] = (bf16)(hv * t0.y);
            a[2] = (bf16)(hv * t0.z); a[3] = (bf16)(hv * t0.w);
            a[4] = (bf16)(hv * t1.x); a[5] = (bf16)(hv * t1.y);
            a[6] = (bf16)(hv * t1.z); a[7] = (bf16)(hv * t1.w);
            int ck = s * 2 + kg;
            bf16x8 b0 = ((const bf16x8*)Wl)[rr0 * 8 + (ck ^ (rr0 & 7))];
            bf16x8 b1 = ((const bf16x8*)Wl)[rr1 * 8 + (ck ^ (rr1 & 7))];
            acc0 = __builtin_amdgcn_mfma_f32_32x32x16_bf16(a, b0, acc0, 0, 0, 0);
            acc1 = __builtin_amdgcn_mfma_f32_32x32x16_bf16(a, b1, acc1, 0, 0, 0);
        }
    }
#pragma unroll
    for (int reg = 0; reg < 16; ++reg) {
        int row = (reg & 3) + 8 * (reg >> 2) + 4 * kg;
        int bp = bp0 + w_m * 32 + row;
        if (rr0 < Rc) atomicAdd(&outp[(size_t)bp * Rc + rr0], acc0[reg]);
        if (rr1 < Rc) atomicAdd(&outp[(size_t)bp * Rc + rr1], acc1[reg]);
    }
}

extern "C" void kernel_launch(void* const* d_in, const int* in_sizes, int n_in,
                              void* d_out, int out_size, void* d_ws, size_t ws_size,
                              hipStream_t stream) {
    const float* context   = (const float*)d_in[0];
    const float* attention = (const float*)d_in[1];
    const float* mm        = (const float*)d_in[2];
    const float* em        = (const float*)d_in[3];
    const int*   hts       = (const int*)d_in[4];
    const float* hW        = (const float*)d_in[5];
    const float* hb        = (const float*)d_in[6];
    const float* tW        = (const float*)d_in[7];
    const float* tb        = (const float*)d_in[8];
    const float* hcW       = (const float*)d_in[9];
    const float* hcb       = (const float*)d_in[10];
    const float* tcW       = (const float*)d_in[11];
    const float* tcb       = (const float*)d_in[12];
    const float* clasW     = (const float*)d_in[13];
    const float* clasb     = (const float*)d_in[14];
    float* out = (float*)d_out;

    char* wsb = (char*)d_ws;
    auto alloc = [&](size_t bytes) { char* p = wsb; wsb += (bytes + 255) & ~(size_t)255; return p; };
    float* mention     = (float*)alloc((size_t)Bc * Mc * Dc * 4);
    float* att_sum     = (float*)alloc((size_t)Bc * Lc * Lc * 4);
    float* tmpML       = (float*)alloc((size_t)Bc * Mc * Lc * 4);
    float* mention_att = (float*)alloc((size_t)Bc * Mc * Mc * 4);
    float* entity_att  = (float*)alloc((size_t)Bc * Ec * Mc * 4);
    float* em_tok      = (float*)alloc((size_t)Bc * Ec * Lc * 4);
    float* ent_att     = (float*)alloc((size_t)Bc * Hc * Ec * Lc * 4);
    float* ctx_att     = (float*)alloc((size_t)Bc * Pc * Lc * 4);
    bf16* h_buf   = (bf16*)alloc((size_t)Bc * Pc * Dc * 2);
    bf16* t_buf   = (bf16*)alloc((size_t)Bc * Pc * Dc * 2);
    bf16* ctxinfo = (bf16*)alloc((size_t)Bc * Pc * Dc * 2);
    bf16* h_fin   = (bf16*)alloc((size_t)Bc * Pc * Dc * 2);
    bf16* t_fin   = (bf16*)alloc((size_t)Bc * Pc * Dc * 2);
    bf16* hWb     = (bf16*)alloc((size_t)Dc * Dc * 2);
    bf16* tWb     = (bf16*)alloc((size_t)Dc * Dc * 2);
    bf16* hcWb    = (bf16*)alloc((size_t)Dc * Dc * 2);
    bf16* tcWb    = (bf16*)alloc((size_t)Dc * Dc * 2);
    bf16* clasWb  = (bf16*)alloc((size_t)Rc * Dc * 64 * 2);

    const int DD = Dc * Dc;
    const int CW = Rc * Dc * 64;
    k_cvt<<<dim3(288), dim3(256), 0, stream>>>(hW, hWb, DD);
    k_cvt<<<dim3(288), dim3(256), 0, stream>>>(tW, tWb, DD);
    k_cvt<<<dim3(288), dim3(256), 0, stream>>>(hcW, hcWb, DD);
    k_cvt<<<dim3(288), dim3(256), 0, stream>>>(tcW, tcWb, DD);
    k_cvt<<<dim3(2048), dim3(256), 0, stream>>>(clasW, clasWb, CW);

    k_attsum<<<dim3((Bc * Lc * Lc + 255) / 256), dim3(256), 0, stream>>>(attention, att_sum);
    k_mention<<<dim3(Bc * Mc), dim3(256), 0, stream>>>(mm, context, mention);
    k_mm_attsum<<<dim3(Bc * Mc), dim3(256), 0, stream>>>(mm, att_sum, tmpML);
    k_mention_att<<<dim3((Bc * Mc * Mc + 255) / 256), dim3(256), 0, stream>>>(tmpML, mm, mention_att);
    k_entity_att<<<dim3((Bc * Ec * Mc + 255) / 256), dim3(256), 0, stream>>>(em, mention_att, entity_att);
    k_ht<<<dim3(Bc * Pc), dim3(256), 0, stream>>>(hts, em, entity_att, mention, h_buf, t_buf);
    k_emtok<<<dim3(Bc * Ec), dim3(256), 0, stream>>>(em, mm, em_tok);
    k_entatt<<<dim3(Bc * Hc * Ec), dim3(256), 0, stream>>>(em_tok, attention, ent_att);
    k_ctxatt<<<dim3(Bc * Pc), dim3(256), 0, stream>>>(hts, ent_att, ctx_att);
    k_ctxinfo<<<dim3(Bc * (Pc / 8) * 3), dim3(256), 0, stream>>>(hts, ctx_att, context, ctxinfo);
    k_proj_mfma<<<dim3(32, 12), dim3(256), 0, stream>>>(h_buf, hWb, hb, ctxinfo, hcWb, hcb, h_fin);
    k_proj_mfma<<<dim3(32, 12), dim3(256), 0, stream>>>(t_buf, tWb, tb, ctxinfo, tcWb, tcb, t_fin);
    k_outinit<<<dim3((Bc * Pc * Rc + 255) / 256), dim3(256), 0, stream>>>(clasb, out);
    k_bilin_mfma<<<dim3(32, 12), dim3(256), 0, stream>>>(h_fin, t_fin, clasWb, out);
}

// Round 3
// 506.366 us; speedup vs baseline: 2.7268x; 1.1744x over previous
//
#include <hip/hip_runtime.h>
#include <math.h>

#define Bc 4
#define Lc 512
#define Dc 768
#define Hc 12
#define Mc 48
#define Ec 32
#define Pc 512
#define Rc 97
#define MINV 1e-30f

typedef __bf16 bf16;
typedef __attribute__((ext_vector_type(8))) __bf16 bf16x8;
typedef __attribute__((ext_vector_type(4))) __bf16 bf16x4;
typedef __attribute__((ext_vector_type(16))) float f32x16;

// ---------------- K0: fp32 -> bf16 convert ----------------
__global__ __launch_bounds__(256) void k_cvt(const float* __restrict__ s, bf16* __restrict__ d, int nElem) {
    int i = blockIdx.x * 256 + threadIdx.x;
    int stride = gridDim.x * 256;
    for (; i < nElem; i += stride) d[i] = (bf16)s[i];
}

// ---------------- K1: mention[b,m,d] = sum_l mm[b,m,l] * context[b,l,d] ----------------
__global__ __launch_bounds__(256) void k_mention(const float* __restrict__ mm,
                                                 const float* __restrict__ ctx,
                                                 float* __restrict__ mention) {
    int bm = blockIdx.x; int b = bm / Mc;
    __shared__ float row[Lc];
    for (int l = threadIdx.x; l < Lc; l += 256) row[l] = mm[(size_t)bm * Lc + l];
    __syncthreads();
    for (int d = threadIdx.x; d < Dc; d += 256) {
        float acc = 0.f;
        const float* cb = ctx + (size_t)b * Lc * Dc + d;
        for (int l = 0; l < Lc; ++l) acc += row[l] * cb[(size_t)l * Dc];
        mention[(size_t)bm * Dc + d] = acc;
    }
}

// ---------------- K2: att_sum[b,i,j] = sum_h attention[b,h,i,j] ----------------
__global__ __launch_bounds__(256) void k_attsum(const float* __restrict__ att,
                                                float* __restrict__ as_) {
    int idx = blockIdx.x * 256 + threadIdx.x;
    if (idx >= Bc * Lc * Lc) return;
    int b = idx / (Lc * Lc); int rem = idx % (Lc * Lc);
    float acc = 0.f;
    const float* p = att + (size_t)b * Hc * Lc * Lc + rem;
    for (int h = 0; h < Hc; ++h) acc += p[(size_t)h * Lc * Lc];
    as_[idx] = acc;
}

// ---------------- K3a: tmpML[b,m,j] = sum_i mm[b,m,i] * att_sum[b,i,j] ----------------
__global__ __launch_bounds__(256) void k_mm_attsum(const float* __restrict__ mm,
                                                   const float* __restrict__ as_,
                                                   float* __restrict__ tmp) {
    int bm = blockIdx.x; int b = bm / Mc;
    __shared__ float row[Lc];
    for (int l = threadIdx.x; l < Lc; l += 256) row[l] = mm[(size_t)bm * Lc + l];
    __syncthreads();
    for (int j = threadIdx.x; j < Lc; j += 256) {
        float acc = 0.f;
        const float* ab = as_ + (size_t)b * Lc * Lc + j;
        for (int i = 0; i < Lc; ++i) acc += row[i] * ab[(size_t)i * Lc];
        tmp[(size_t)bm * Lc + j] = acc;
    }
}

// ---------------- K3b: mention_att[b,m,m2] = sum_j tmp[b,m,j]*mm[b,m2,j] ----------------
__global__ __launch_bounds__(256) void k_mention_att(const float* __restrict__ tmp,
                                                     const float* __restrict__ mm,
                                                     float* __restrict__ ma) {
    int idx = blockIdx.x * 256 + threadIdx.x;
    if (idx >= Bc * Mc * Mc) return;
    int b = idx / (Mc * Mc); int m = (idx / Mc) % Mc; int m2 = idx % Mc;
    float acc = 0.f;
    const float* t = tmp + (size_t)(b * Mc + m) * Lc;
    const float* r = mm + (size_t)(b * Mc + m2) * Lc;
    for (int j = 0; j < Lc; ++j) acc += t[j] * r[j];
    ma[idx] = acc;
}

// ---------------- K4: entity_att[b,e,m2] = sum_m em[b,e,m]*mention_att[b,m,m2] ----------------
__global__ __launch_bounds__(256) void k_entity_att(const float* __restrict__ em,
                                                    const float* __restrict__ ma,
                                                    float* __restrict__ ea) {
    int idx = blockIdx.x * 256 + threadIdx.x;
    if (idx >= Bc * Ec * Mc) return;
    int b = idx / (Ec * Mc); int e = (idx / Mc) % Ec; int m2 = idx % Mc;
    float acc = 0.f;
    const float* emr = em + (size_t)(b * Ec + e) * Mc;
    const float* mac = ma + (size_t)b * Mc * Mc + m2;
    for (int m = 0; m < Mc; ++m) acc += emr[m] * mac[(size_t)m * Mc];
    ea[idx] = acc;
}

// ---------------- K5: h_att/t_att normalize + h,t = att @ mention (bf16 out) ----------------
__global__ __launch_bounds__(256) void k_ht(const int* __restrict__ hts,
                                            const float* __restrict__ em,
                                            const float* __restrict__ ea,
                                            const float* __restrict__ mention,
                                            bf16* __restrict__ hB, bf16* __restrict__ tB) {
    int bp = blockIdx.x; int b = bp / Pc;
    int hi = hts[bp * 2], ti = hts[bp * 2 + 1];
    float mask = (hi + ti != 0) ? 1.f : 0.f;
    __shared__ float hat[Mc], tat[Mc];
    __shared__ float sums[2];
    int tid = threadIdx.x;
    if (tid < Mc) {
        float hm = em[(size_t)(b * Ec + hi) * Mc + tid];
        float tm = em[(size_t)(b * Ec + ti) * Mc + tid];
        float eh = ea[(size_t)(b * Ec + hi) * Mc + tid];
        float et = ea[(size_t)(b * Ec + ti) * Mc + tid];
        hat[tid] = eh * tm * mask;   // h_att = entity_att[h_idx] * t_mask
        tat[tid] = et * hm * mask;   // t_att = entity_att[t_idx] * h_mask
    }
    __syncthreads();
    if (tid == 0) {
        float sh = 0.f, st = 0.f;
        for (int m = 0; m < Mc; ++m) { sh += hat[m]; st += tat[m]; }
        sums[0] = 1.f / (sh + MINV);
        sums[1] = 1.f / (st + MINV);
    }
    __syncthreads();
    float hnorm = sums[0], tnorm = sums[1];
    for (int d = tid; d < Dc; d += 256) {
        float ah = 0.f, at = 0.f;
        const float* mb = mention + (size_t)b * Mc * Dc + d;
        for (int m = 0; m < Mc; ++m) {
            float mv = mb[(size_t)m * Dc];
            ah += tat[m] * mv;   // h = t_att @ mention
            at += hat[m] * mv;   // t = h_att @ mention
        }
        hB[(size_t)bp * Dc + d] = (bf16)(ah * tnorm * mask);
        tB[(size_t)bp * Dc + d] = (bf16)(at * hnorm * mask);
    }
}

// ---------------- K6: em_tok[b,e,l] normalized ----------------
__global__ __launch_bounds__(256) void k_emtok(const float* __restrict__ em,
                                               const float* __restrict__ mm,
                                               float* __restrict__ emt) {
    int be = blockIdx.x; int b = be / Ec;
    __shared__ float row[Mc];
    __shared__ float red[256];
    __shared__ float inv;
    int tid = threadIdx.x;
    if (tid < Mc) row[tid] = em[(size_t)be * Mc + tid];
    __syncthreads();
    float v0 = 0.f, v1 = 0.f;
    {
        const float* mb0 = mm + (size_t)b * Mc * Lc + tid;
        const float* mb1 = mm + (size_t)b * Mc * Lc + tid + 256;
        for (int m = 0; m < Mc; ++m) {
            v0 += row[m] * mb0[(size_t)m * Lc];
            v1 += row[m] * mb1[(size_t)m * Lc];
        }
    }
    red[tid] = v0 + v1;
    __syncthreads();
    for (int s = 128; s > 0; s >>= 1) { if (tid < s) red[tid] += red[tid + s]; __syncthreads(); }
    if (tid == 0) inv = 1.f / (red[0] + MINV);
    __syncthreads();
    emt[(size_t)be * Lc + tid] = v0 * inv;
    emt[(size_t)be * Lc + tid + 256] = v1 * inv;
}

// ---------------- K7 v2: ent_att via MFMA. Per (b,h): eat[32e, m] = emt[32e, l] @ att[l, m] ----------------
// grid = 48 bh * 4 m-tiles(128). Block 256 thr = 4 waves, wave -> 32e x 32m tile.
__global__ __launch_bounds__(256) void k_entatt2(const float* __restrict__ emt,
                                                 const float* __restrict__ att,
                                                 float* __restrict__ eat) {
    __shared__ __align__(16) bf16 emtS[32 * 64 * 8];   // [e][64 l-chunks(^e&7)][8] = 32 KB
    __shared__ __align__(16) bf16 attS[128 * 8 * 8];   // [m][8 l-chunks(^m&7)][8] = 16 KB
    int id = blockIdx.x;
    int mt = id & 3; int bh = id >> 2;
    int b = bh / Hc, h = bh % Hc;
    int m0 = mt * 128;
    int tid = threadIdx.x;
    int w = tid >> 6, lane = tid & 63;
    int n_l = lane & 31, kg = lane >> 5;

    // stage emt (fp32 -> bf16), swizzled chunks
    {
        int e = tid >> 3; int cbase = (tid & 7) * 8;
        const float* src = emt + (size_t)(b * Ec + e) * Lc;
#pragma unroll
        for (int j = 0; j < 8; ++j) {
            int cc = cbase + j;
            bf16x8 v;
#pragma unroll
            for (int jj = 0; jj < 8; ++jj) v[jj] = (bf16)src[cc * 8 + jj];
            ((bf16x8*)emtS)[e * 64 + (cc ^ (e & 7))] = v;
        }
    }
    f32x16 acc;
#pragma unroll
    for (int i = 0; i < 16; ++i) acc[i] = 0.f;

    const float* ab = att + (size_t)(b * Hc + h) * Lc * Lc + m0;
    int mRow = tid & 127; int lg = tid >> 7;   // lg: l-half of chunk
    float pre[32];
#pragma unroll
    for (int q = 0; q < 32; ++q) pre[q] = ab[(size_t)(lg * 32 + q) * Lc + mRow];

    int mr = w * 32 + n_l;
    for (int kc = 0; kc < 8; ++kc) {
        __syncthreads();   // prev compute done -> safe to overwrite attS
#pragma unroll
        for (int q8 = 0; q8 < 4; ++q8) {
            int cc = lg * 4 + q8;
            bf16x8 v;
#pragma unroll
            for (int jj = 0; jj < 8; ++jj) v[jj] = (bf16)pre[q8 * 8 + jj];
            ((bf16x8*)attS)[mRow * 8 + (cc ^ (mRow & 7))] = v;
        }
        if (kc < 7) {
#pragma unroll
            for (int q = 0; q < 32; ++q)
                pre[q] = ab[(size_t)((kc + 1) * 64 + lg * 32 + q) * Lc + mRow];
        }
        __syncthreads();
#pragma unroll
        for (int s = 0; s < 4; ++s) {
            int ccA = kc * 8 + s * 2 + kg;
            bf16x8 a = ((const bf16x8*)emtS)[n_l * 64 + (ccA ^ (n_l & 7))];
            int ccB = s * 2 + kg;
            bf16x8 bb = ((const bf16x8*)attS)[mr * 8 + (ccB ^ (mr & 7))];
            acc = __builtin_amdgcn_mfma_f32_32x32x16_bf16(a, bb, acc, 0, 0, 0);
        }
    }
#pragma unroll
    for (int reg = 0; reg < 16; ++reg) {
        int e = (reg & 3) + 8 * (reg >> 2) + 4 * kg;
        eat[((size_t)(b * Hc + h) * Ec + e) * Lc + m0 + w * 32 + n_l] = acc[reg];
    }
}

// ---------------- K8: ctx_att[b,p,l] = sum_h eat[b,h,hi,l]*eat[b,h,ti,l], normalized ----------------
__global__ __launch_bounds__(256) void k_ctxatt(const int* __restrict__ hts,
                                                const float* __restrict__ eat,
                                                float* __restrict__ ca) {
    int bp = blockIdx.x; int b = bp / Pc;
    int hi = hts[bp * 2], ti = hts[bp * 2 + 1];
    int tid = threadIdx.x;
    float a0 = 0.f, a1 = 0.f;
    for (int h = 0; h < Hc; ++h) {
        const float* ph = eat + ((size_t)(b * Hc + h) * Ec + hi) * Lc;
        const float* pt = eat + ((size_t)(b * Hc + h) * Ec + ti) * Lc;
        a0 += ph[tid] * pt[tid];
        a1 += ph[tid + 256] * pt[tid + 256];
    }
    __shared__ float red[256];
    __shared__ float inv;
    red[tid] = a0 + a1;
    __syncthreads();
    for (int s = 128; s > 0; s >>= 1) { if (tid < s) red[tid] += red[tid + s]; __syncthreads(); }
    if (tid == 0) inv = 1.f / (red[0] + MINV);
    __syncthreads();
    ca[(size_t)bp * Lc + tid] = a0 * inv;
    ca[(size_t)bp * Lc + tid + 256] = a1 * inv;
}

// ---------------- K9: context_info[b,p,d] = (ctx_att @ context) * mask (bf16 out) ----------------
__global__ __launch_bounds__(256) void k_ctxinfo(const int* __restrict__ hts,
                                                 const float* __restrict__ ca,
                                                 const float* __restrict__ ctx,
                                                 bf16* __restrict__ ci) {
    int bt = blockIdx.x;
    int dt = bt % 3; int pt = (bt / 3) % (Pc / 8); int b = bt / (3 * (Pc / 8));
    int p0 = pt * 8;
    __shared__ float rows[8][Lc];
    __shared__ float masks[8];
    int tid = threadIdx.x;
    for (int idx = tid; idx < 8 * Lc; idx += 256) {
        int k = idx / Lc, l = idx % Lc;
        rows[k][l] = ca[(size_t)(b * Pc + p0 + k) * Lc + l];
    }
    if (tid < 8) {
        int bp = b * Pc + p0 + tid;
        masks[tid] = (hts[bp * 2] + hts[bp * 2 + 1] != 0) ? 1.f : 0.f;
    }
    __syncthreads();
    int d = dt * 256 + tid;
    float acc[8] = {0.f, 0.f, 0.f, 0.f, 0.f, 0.f, 0.f, 0.f};
    const float* cb = ctx + (size_t)b * Lc * Dc + d;
    for (int l = 0; l < Lc; ++l) {
        float cv = cb[(size_t)l * Dc];
#pragma unroll
        for (int k = 0; k < 8; ++k) acc[k] += rows[k][l] * cv;
    }
#pragma unroll
    for (int k = 0; k < 8; ++k)
        ci[(size_t)(b * Pc + p0 + k) * Dc + d] = (bf16)(acc[k] * masks[k]);
}

// ---------------- K10: MFMA proj (1-barrier double-buffered) ----------------
__global__ __launch_bounds__(256) void k_proj_mfma(const bf16* __restrict__ X1, const bf16* __restrict__ W1,
                                                   const float* __restrict__ b1,
                                                   const bf16* __restrict__ X2, const bf16* __restrict__ W2,
                                                   const float* __restrict__ b2,
                                                   bf16* __restrict__ outp) {
    __shared__ __align__(16) bf16 Xs[2][64 * 64];
    __shared__ __align__(16) bf16 Ws[2][64 * 64];
    int m0 = blockIdx.x * 64, n0 = blockIdx.y * 64;
    int tid = threadIdx.x;
    int w = tid >> 6, lane = tid & 63;
    int w_m = w & 1, w_n = w >> 1;
    int m_l = lane & 31, kg = lane >> 5;
    const bf16* Xarr[2] = {X1, X2};
    const bf16* Warr[2] = {W1, W2};
    int r0 = tid >> 3, cc0 = tid & 7;
    int r1 = r0 + 32;
    bf16x8 xr0, xr1, wr0, wr1;
    auto loadt = [&](int it) {
        int src = it / 12; int k0 = (it % 12) * 64;
        const bf16* X = Xarr[src]; const bf16* W = Warr[src];
        xr0 = *(const bf16x8*)(X + (size_t)(m0 + r0) * Dc + k0 + cc0 * 8);
        xr1 = *(const bf16x8*)(X + (size_t)(m0 + r1) * Dc + k0 + cc0 * 8);
        wr0 = *(const bf16x8*)(W + (size_t)(n0 + r0) * Dc + k0 + cc0 * 8);
        wr1 = *(const bf16x8*)(W + (size_t)(n0 + r1) * Dc + k0 + cc0 * 8);
    };
    auto writet = [&](int p) {
        ((bf16x8*)Xs[p])[r0 * 8 + (cc0 ^ (r0 & 7))] = xr0;
        ((bf16x8*)Xs[p])[r1 * 8 + (cc0 ^ (r1 & 7))] = xr1;
        ((bf16x8*)Ws[p])[r0 * 8 + (cc0 ^ (r0 & 7))] = wr0;
        ((bf16x8*)Ws[p])[r1 * 8 + (cc0 ^ (r1 & 7))] = wr1;
    };
    loadt(0);
    writet(0);
    loadt(1);
    f32x16 acc;
#pragma unroll
    for (int i = 0; i < 16; ++i) acc[i] = 0.f;
    int ar = w_m * 32 + m_l;
    int br = w_n * 32 + m_l;
    for (int it = 0; it < 24; ++it) {
        int p = it & 1;
        __syncthreads();
        if (it < 23) writet(p ^ 1);
        if (it < 22) loadt(it + 2);
#pragma unroll
        for (int s = 0; s < 4; ++s) {
            int ck = s * 2 + kg;
            bf16x8 a = ((const bf16x8*)Xs[p])[ar * 8 + (ck ^ (ar & 7))];
            bf16x8 b = ((const bf16x8*)Ws[p])[br * 8 + (ck ^ (br & 7))];
            acc = __builtin_amdgcn_mfma_f32_32x32x16_bf16(a, b, acc, 0, 0, 0);
        }
    }
#pragma unroll
    for (int reg = 0; reg < 16; ++reg) {
        int row = (reg & 3) + 8 * (reg >> 2) + 4 * kg;
        int m = m0 + w_m * 32 + row;
        int n = n0 + w_n * 32 + m_l;
        float v = tanhf(acc[reg] + b1[n] + b2[n]);
        outp[(size_t)m * Dc + n] = (bf16)v;
    }
}

// ---------------- K11a: init out with bias ----------------
__global__ __launch_bounds__(256) void k_outinit(const float* __restrict__ cb, float* __restrict__ out) {
    int idx = blockIdx.x * 256 + threadIdx.x;
    if (idx < Bc * Pc * Rc) out[idx] = cb[idx % Rc];
}

// ---------------- K11b prep: swizzle clasW into MFMA-fragment layout ----------------
// frag f = (c*4+s)*4+rt ; elem: lane=(kg*32+n_l): Wp[f*512 + lane*8 + j] = clasW[r=rt*32+n_l][c*64+s*16+kg*8+j]
__global__ __launch_bounds__(256) void k_wprep(const float* __restrict__ W, bf16* __restrict__ Wp) {
    int gid = blockIdx.x * 256 + threadIdx.x;
    if (gid >= 768 * 16 * 64) return;
    int lane = gid & 63; int f = gid >> 6;
    int rt = f & 3; int s = (f >> 2) & 3; int c = f >> 4;
    int n_l = lane & 31, kg = lane >> 5;
    int r = rt * 32 + n_l;
    bf16x8 v;
    if (r < Rc) {
        const float* src = W + (size_t)r * (Dc * 64) + c * 64 + s * 16 + kg * 8;
#pragma unroll
        for (int j = 0; j < 8; ++j) v[j] = (bf16)src[j];
    } else {
#pragma unroll
        for (int j = 0; j < 8; ++j) v[j] = (bf16)0.f;
    }
    ((bf16x8*)Wp)[gid] = v;
}

// ---------------- K11b v2: group bilinear, B-frags direct from global (pre-swizzled) ----------------
// grid = 16 bp-tiles(128) x 32 k-slices (24 chunks each); id = tile*32 + slice -> XCD=slice%8.
// Block 256 thr = 4 waves: w_m = bp-half(64), w_i = chunk parity. Wave: 64bp x 128r, acc 2x4 tiles.
__global__ __launch_bounds__(256, 2) void k_bilin2(const bf16* __restrict__ hF, const bf16* __restrict__ tF,
                                                   const bf16* __restrict__ Wp, float* __restrict__ outp) {
    __shared__ float smem[128 * 68 + 128 * 25];   // t[128][68] fp32 | h[128][25] fp32 ; epilogue aliases as [128][64]
    float* tS = smem;
    float* hS = smem + 128 * 68;
    float* mbuf = smem;
    int id = blockIdx.x;
    int tile = id >> 5;
    int slice = id & 31;
    int bp0 = tile * 128;
    int tid = threadIdx.x;
    int w = tid >> 6, lane = tid & 63;
    int w_m = w & 1, w_i = w >> 1;
    int m_l = lane & 31, kg = lane >> 5;
    int c0 = slice * 24, cEnd = c0 + 24;

    // stage h window (fp32): h index for chunk c is simply c (n*64+i == c)
    for (int idx = tid; idx < 128 * 24; idx += 256) {
        int bp = idx / 24, i = idx % 24;
        hS[bp * 25 + i] = (float)hF[(size_t)(bp0 + bp) * Dc + c0 + i];
    }

    f32x16 acc[2][4];
#pragma unroll
    for (int mt = 0; mt < 2; ++mt)
#pragma unroll
        for (int rt = 0; rt < 4; ++rt)
#pragma unroll
            for (int i = 0; i < 16; ++i) acc[mt][rt][i] = 0.f;

    int rowA = w_m * 64 + m_l;
    int rowB = rowA + 32;

    int c = c0;
    while (c < cEnd) {
        int n = c >> 6;
        int segEnd = (cEnd < (n + 1) * 64) ? cEnd : (n + 1) * 64;
        __syncthreads();
        for (int idx = tid; idx < 128 * 64; idx += 256) {
            int bp = idx >> 6, j = idx & 63;
            tS[bp * 68 + j] = (float)tF[(size_t)(bp0 + bp) * Dc + n * 64 + j];
        }
        __syncthreads();
        for (int cc = c + w_i; cc < segEnd; cc += 2) {
            int ii = cc - c0;
            float hv0 = hS[rowA * 25 + ii];
            float hv1 = hS[rowB * 25 + ii];
            const bf16x8* wpb = (const bf16x8*)Wp + (size_t)cc * 16 * 64 + lane;
#pragma unroll
            for (int s = 0; s < 4; ++s) {
                const float* tp0 = &tS[rowA * 68 + s * 16 + kg * 8];
                const float* tp1 = &tS[rowB * 68 + s * 16 + kg * 8];
                bf16x8 a0, a1;
#pragma unroll
                for (int j = 0; j < 8; ++j) {
                    a0[j] = (bf16)(hv0 * tp0[j]);
                    a1[j] = (bf16)(hv1 * tp1[j]);
                }
                bf16x8 B0 = wpb[(s * 4 + 0) * 64];
                bf16x8 B1 = wpb[(s * 4 + 1) * 64];
                bf16x8 B2 = wpb[(s * 4 + 2) * 64];
                bf16x8 B3 = wpb[(s * 4 + 3) * 64];
                acc[0][0] = __builtin_amdgcn_mfma_f32_32x32x16_bf16(a0, B0, acc[0][0], 0, 0, 0);
                acc[1][0] = __builtin_amdgcn_mfma_f32_32x32x16_bf16(a1, B0, acc[1][0], 0, 0, 0);
                acc[0][1] = __builtin_amdgcn_mfma_f32_32x32x16_bf16(a0, B1, acc[0][1], 0, 0, 0);
                acc[1][1] = __builtin_amdgcn_mfma_f32_32x32x16_bf16(a1, B1, acc[1][1], 0, 0, 0);
                acc[0][2] = __builtin_amdgcn_mfma_f32_32x32x16_bf16(a0, B2, acc[0][2], 0, 0, 0);
                acc[1][2] = __builtin_amdgcn_mfma_f32_32x32x16_bf16(a1, B2, acc[1][2], 0, 0, 0);
                acc[0][3] = __builtin_amdgcn_mfma_f32_32x32x16_bf16(a0, B3, acc[0][3], 0, 0, 0);
                acc[1][3] = __builtin_amdgcn_mfma_f32_32x32x16_bf16(a1, B3, acc[1][3], 0, 0, 0);
            }
        }
        c = segEnd;
    }

    // epilogue: merge w_i pairs via LDS (2 rounds over r-halves), then atomicAdd
    for (int R = 0; R < 2; ++R) {
        __syncthreads();
        if (w_i == 1) {
#pragma unroll
            for (int mt = 0; mt < 2; ++mt)
#pragma unroll
                for (int q = 0; q < 2; ++q) {
                    int rt = R * 2 + q;
#pragma unroll
                    for (int reg = 0; reg < 16; ++reg) {
                        int row = (reg & 3) + 8 * (reg >> 2) + 4 * kg;
                        mbuf[(w_m * 64 + mt * 32 + row) * 64 + q * 32 + m_l] = acc[mt][rt][reg];
                    }
                }
        }
        __syncthreads();
        if (w_i == 0) {
#pragma unroll
            for (int mt = 0; mt < 2; ++mt)
#pragma unroll
                for (int q = 0; q < 2; ++q) {
                    int rt = R * 2 + q;
                    int r = rt * 32 + m_l;
                    if (r < Rc) {
#pragma unroll
                        for (int reg = 0; reg < 16; ++reg) {
                            int row = (reg & 3) + 8 * (reg >> 2) + 4 * kg;
                            int bp = bp0 + w_m * 64 + mt * 32 + row;
                            float v = acc[mt][rt][reg] + mbuf[(w_m * 64 + mt * 32 + row) * 64 + q * 32 + m_l];
                            atomicAdd(&outp[(size_t)bp * Rc + r], v);
                        }
                    }
                }
        }
    }
}

extern "C" void kernel_launch(void* const* d_in, const int* in_sizes, int n_in,
                              void* d_out, int out_size, void* d_ws, size_t ws_size,
                              hipStream_t stream) {
    const float* context   = (const float*)d_in[0];
    const float* attention = (const float*)d_in[1];
    const float* mm        = (const float*)d_in[2];
    const float* em        = (const float*)d_in[3];
    const int*   hts       = (const int*)d_in[4];
    const float* hW        = (const float*)d_in[5];
    const float* hb        = (const float*)d_in[6];
    const float* tW        = (const float*)d_in[7];
    const float* tb        = (const float*)d_in[8];
    const float* hcW       = (const float*)d_in[9];
    const float* hcb       = (const float*)d_in[10];
    const float* tcW       = (const float*)d_in[11];
    const float* tcb       = (const float*)d_in[12];
    const float* clasW     = (const float*)d_in[13];
    const float* clasb     = (const float*)d_in[14];
    float* out = (float*)d_out;

    char* wsb = (char*)d_ws;
    auto alloc = [&](size_t bytes) { char* p = wsb; wsb += (bytes + 255) & ~(size_t)255; return p; };
    float* mention     = (float*)alloc((size_t)Bc * Mc * Dc * 4);
    float* att_sum     = (float*)alloc((size_t)Bc * Lc * Lc * 4);
    float* tmpML       = (float*)alloc((size_t)Bc * Mc * Lc * 4);
    float* mention_att = (float*)alloc((size_t)Bc * Mc * Mc * 4);
    float* entity_att  = (float*)alloc((size_t)Bc * Ec * Mc * 4);
    float* em_tok      = (float*)alloc((size_t)Bc * Ec * Lc * 4);
    float* ent_att     = (float*)alloc((size_t)Bc * Hc * Ec * Lc * 4);
    float* ctx_att     = (float*)alloc((size_t)Bc * Pc * Lc * 4);
    bf16* h_buf   = (bf16*)alloc((size_t)Bc * Pc * Dc * 2);
    bf16* t_buf   = (bf16*)alloc((size_t)Bc * Pc * Dc * 2);
    bf16* ctxinfo = (bf16*)alloc((size_t)Bc * Pc * Dc * 2);
    bf16* h_fin   = (bf16*)alloc((size_t)Bc * Pc * Dc * 2);
    bf16* t_fin   = (bf16*)alloc((size_t)Bc * Pc * Dc * 2);
    bf16* hWb     = (bf16*)alloc((size_t)Dc * Dc * 2);
    bf16* tWb     = (bf16*)alloc((size_t)Dc * Dc * 2);
    bf16* hcWb    = (bf16*)alloc((size_t)Dc * Dc * 2);
    bf16* tcWb    = (bf16*)alloc((size_t)Dc * Dc * 2);
    bf16* Wp      = (bf16*)alloc((size_t)768 * 16 * 64 * 8 * 2);   // 12.58 MB swizzled clasW

    const int DD = Dc * Dc;
    k_cvt<<<dim3(288), dim3(256), 0, stream>>>(hW, hWb, DD);
    k_cvt<<<dim3(288), dim3(256), 0, stream>>>(tW, tWb, DD);
    k_cvt<<<dim3(288), dim3(256), 0, stream>>>(hcW, hcWb, DD);
    k_cvt<<<dim3(288), dim3(256), 0, stream>>>(tcW, tcWb, DD);
    k_wprep<<<dim3(3072), dim3(256), 0, stream>>>(clasW, Wp);

    k_attsum<<<dim3((Bc * Lc * Lc + 255) / 256), dim3(256), 0, stream>>>(attention, att_sum);
    k_mention<<<dim3(Bc * Mc), dim3(256), 0, stream>>>(mm, context, mention);
    k_mm_attsum<<<dim3(Bc * Mc), dim3(256), 0, stream>>>(mm, att_sum, tmpML);
    k_mention_att<<<dim3((Bc * Mc * Mc + 255) / 256), dim3(256), 0, stream>>>(tmpML, mm, mention_att);
    k_entity_att<<<dim3((Bc * Ec * Mc + 255) / 256), dim3(256), 0, stream>>>(em, mention_att, entity_att);
    k_ht<<<dim3(Bc * Pc), dim3(256), 0, stream>>>(hts, em, entity_att, mention, h_buf, t_buf);
    k_emtok<<<dim3(Bc * Ec), dim3(256), 0, stream>>>(em, mm, em_tok);
    k_entatt2<<<dim3(Bc * Hc * 4), dim3(256), 0, stream>>>(em_tok, attention, ent_att);
    k_ctxatt<<<dim3(Bc * Pc), dim3(256), 0, stream>>>(hts, ent_att, ctx_att);
    k_ctxinfo<<<dim3(Bc * (Pc / 8) * 3), dim3(256), 0, stream>>>(hts, ctx_att, context, ctxinfo);
    k_proj_mfma<<<dim3(32, 12), dim3(256), 0, stream>>>(h_buf, hWb, hb, ctxinfo, hcWb, hcb, h_fin);
    k_proj_mfma<<<dim3(32, 12), dim3(256), 0, stream>>>(t_buf, tWb, tb, ctxinfo, tcWb, tcb, t_fin);
    k_outinit<<<dim3((Bc * Pc * Rc + 255) / 256), dim3(256), 0, stream>>>(clasb, out);
    k_bilin2<<<dim3(512), dim3(256), 0, stream>>>(h_fin, t_fin, Wp, out);
}

// Round 4
// 414.018 us; speedup vs baseline: 3.3350x; 1.2231x over previous
//
#include <hip/hip_runtime.h>
#include <math.h>

#define Bc 4
#define Lc 512
#define Dc 768
#define Hc 12
#define Mc 48
#define Ec 32
#define Pc 512
#define Rc 97
#define MINV 1e-30f

typedef __bf16 bf16;
typedef __attribute__((ext_vector_type(8))) __bf16 bf16x8;
typedef __attribute__((ext_vector_type(4))) __bf16 bf16x4;
typedef __attribute__((ext_vector_type(16))) float f32x16;

// ---------------- K0: fused fp32 -> bf16 convert for 4 DxD weights ----------------
__global__ __launch_bounds__(256) void k_cvt4(const float* __restrict__ s0, const float* __restrict__ s1,
                                              const float* __restrict__ s2, const float* __restrict__ s3,
                                              bf16* __restrict__ d0, bf16* __restrict__ d1,
                                              bf16* __restrict__ d2, bf16* __restrict__ d3) {
    const int DD = Dc * Dc;
    int i = blockIdx.x * 256 + threadIdx.x;
    int stride = gridDim.x * 256;
    for (; i < 4 * DD; i += stride) {
        int sel = i / DD, j = i % DD;
        const float* s = (sel == 0) ? s0 : (sel == 1) ? s1 : (sel == 2) ? s2 : s3;
        bf16* d = (sel == 0) ? d0 : (sel == 1) ? d1 : (sel == 2) ? d2 : d3;
        d[j] = (bf16)s[j];
    }
}

// ---------------- K0b: transpose context -> ctxT[b][d][l] bf16 ----------------
__global__ __launch_bounds__(256) void k_tran(const float* __restrict__ ctx, bf16* __restrict__ ctxT) {
    int id = blockIdx.x;           // ((b*8+lt)*12+dt)
    int dt = id % 12; int lt = (id / 12) % 8; int b = id / 96;
    int l0 = lt * 64, d0 = dt * 64;
    __shared__ bf16 Ts[64][72];
    int tid = threadIdx.x;
    int r = tid >> 2, cg = tid & 3;
    const float* src = ctx + ((size_t)b * Lc + l0 + r) * Dc + d0 + cg * 16;
#pragma unroll
    for (int u = 0; u < 4; ++u) {
        float4 v = ((const float4*)src)[u];
        Ts[cg * 16 + u * 4 + 0][r] = (bf16)v.x;
        Ts[cg * 16 + u * 4 + 1][r] = (bf16)v.y;
        Ts[cg * 16 + u * 4 + 2][r] = (bf16)v.z;
        Ts[cg * 16 + u * 4 + 3][r] = (bf16)v.w;
    }
    __syncthreads();
    int dr = tid >> 2, seg = tid & 3;
    bf16* dst = ctxT + ((size_t)b * Dc + d0 + dr) * Lc + l0 + seg * 16;
    bf16x8 o0, o1;
#pragma unroll
    for (int j = 0; j < 8; ++j) { o0[j] = Ts[dr][seg * 16 + j]; o1[j] = Ts[dr][seg * 16 + 8 + j]; }
    *(bf16x8*)dst = o0;
    *(bf16x8*)(dst + 8) = o1;
}

// ---------------- K1: mention[b,m,d] = sum_l mm[b,m,l] * context[b,l,d] ----------------
__global__ __launch_bounds__(256) void k_mention(const float* __restrict__ mm,
                                                 const float* __restrict__ ctx,
                                                 float* __restrict__ mention) {
    int id = blockIdx.x;
    int dt = id % 3; int bm = id / 3; int b = bm / Mc;
    __shared__ float row[Lc];
    for (int l = threadIdx.x; l < Lc; l += 256) row[l] = mm[(size_t)bm * Lc + l];
    __syncthreads();
    int d = dt * 256 + threadIdx.x;
    float acc = 0.f;
    const float* cb = ctx + (size_t)b * Lc * Dc + d;
    for (int l = 0; l < Lc; ++l) acc += row[l] * cb[(size_t)l * Dc];
    mention[(size_t)bm * Dc + d] = acc;
}

// ---------------- K2: att_sum[b,i,j] = sum_h attention[b,h,i,j] (float4) ----------------
__global__ __launch_bounds__(256) void k_attsum(const float* __restrict__ att,
                                                float* __restrict__ as_) {
    const int Q = Lc * Lc / 4;
    int idx = blockIdx.x * 256 + threadIdx.x;
    if (idx >= Bc * Q) return;
    int b = idx / Q; int rem = idx - b * Q;
    const float4* p = (const float4*)att + (size_t)b * Hc * Q + rem;
    float4 a = make_float4(0.f, 0.f, 0.f, 0.f);
    for (int h = 0; h < Hc; ++h) {
        float4 v = p[(size_t)h * Q];
        a.x += v.x; a.y += v.y; a.z += v.z; a.w += v.w;
    }
    ((float4*)as_)[idx] = a;
}

// ---------------- K3a: tmpML[b,m,j] = sum_i mm[b,m,i] * att_sum[b,i,j] ----------------
__global__ __launch_bounds__(256) void k_mm_attsum(const float* __restrict__ mm,
                                                   const float* __restrict__ as_,
                                                   float* __restrict__ tmp) {
    int id = blockIdx.x;
    int jt = id & 1; int bm = id >> 1; int b = bm / Mc;
    __shared__ float row[Lc];
    for (int l = threadIdx.x; l < Lc; l += 256) row[l] = mm[(size_t)bm * Lc + l];
    __syncthreads();
    int j = jt * 256 + threadIdx.x;
    float acc = 0.f;
    const float* ab = as_ + (size_t)b * Lc * Lc + j;
    for (int i = 0; i < Lc; ++i) acc += row[i] * ab[(size_t)i * Lc];
    tmp[(size_t)bm * Lc + j] = acc;
}

// ---------------- K3b: mention_att[b,m,m2] = sum_j tmp[b,m,j]*mm[b,m2,j] ----------------
__global__ __launch_bounds__(256) void k_mention_att(const float* __restrict__ tmp,
                                                     const float* __restrict__ mm,
                                                     float* __restrict__ ma) {
    int idx = blockIdx.x * 256 + threadIdx.x;
    if (idx >= Bc * Mc * Mc) return;
    int b = idx / (Mc * Mc); int m = (idx / Mc) % Mc; int m2 = idx % Mc;
    float acc = 0.f;
    const float* t = tmp + (size_t)(b * Mc + m) * Lc;
    const float* r = mm + (size_t)(b * Mc + m2) * Lc;
    for (int j = 0; j < Lc; ++j) acc += t[j] * r[j];
    ma[idx] = acc;
}

// ---------------- K4: entity_att[b,e,m2] = sum_m em[b,e,m]*mention_att[b,m,m2] ----------------
__global__ __launch_bounds__(256) void k_entity_att(const float* __restrict__ em,
                                                    const float* __restrict__ ma,
                                                    float* __restrict__ ea) {
    int idx = blockIdx.x * 256 + threadIdx.x;
    if (idx >= Bc * Ec * Mc) return;
    int b = idx / (Ec * Mc); int e = (idx / Mc) % Ec; int m2 = idx % Mc;
    float acc = 0.f;
    const float* emr = em + (size_t)(b * Ec + e) * Mc;
    const float* mac = ma + (size_t)b * Mc * Mc + m2;
    for (int m = 0; m < Mc; ++m) acc += emr[m] * mac[(size_t)m * Mc];
    ea[idx] = acc;
}

// ---------------- K5: h_att/t_att normalize + h,t = att @ mention (bf16 out) ----------------
__global__ __launch_bounds__(256) void k_ht(const int* __restrict__ hts,
                                            const float* __restrict__ em,
                                            const float* __restrict__ ea,
                                            const float* __restrict__ mention,
                                            bf16* __restrict__ hB, bf16* __restrict__ tB) {
    int bp = blockIdx.x; int b = bp / Pc;
    int hi = hts[bp * 2], ti = hts[bp * 2 + 1];
    float mask = (hi + ti != 0) ? 1.f : 0.f;
    __shared__ float hat[Mc], tat[Mc];
    __shared__ float sums[2];
    int tid = threadIdx.x;
    if (tid < Mc) {
        float hm = em[(size_t)(b * Ec + hi) * Mc + tid];
        float tm = em[(size_t)(b * Ec + ti) * Mc + tid];
        float eh = ea[(size_t)(b * Ec + hi) * Mc + tid];
        float et = ea[(size_t)(b * Ec + ti) * Mc + tid];
        hat[tid] = eh * tm * mask;
        tat[tid] = et * hm * mask;
    }
    __syncthreads();
    if (tid == 0) {
        float sh = 0.f, st = 0.f;
        for (int m = 0; m < Mc; ++m) { sh += hat[m]; st += tat[m]; }
        sums[0] = 1.f / (sh + MINV);
        sums[1] = 1.f / (st + MINV);
    }
    __syncthreads();
    float hnorm = sums[0], tnorm = sums[1];
    for (int d = tid; d < Dc; d += 256) {
        float ah = 0.f, at = 0.f;
        const float* mb = mention + (size_t)b * Mc * Dc + d;
        for (int m = 0; m < Mc; ++m) {
            float mv = mb[(size_t)m * Dc];
            ah += tat[m] * mv;
            at += hat[m] * mv;
        }
        hB[(size_t)bp * Dc + d] = (bf16)(ah * tnorm * mask);
        tB[(size_t)bp * Dc + d] = (bf16)(at * hnorm * mask);
    }
}

// ---------------- K6: em_tok[b,e,l] normalized ----------------
__global__ __launch_bounds__(256) void k_emtok(const float* __restrict__ em,
                                               const float* __restrict__ mm,
                                               float* __restrict__ emt) {
    int be = blockIdx.x; int b = be / Ec;
    __shared__ float row[Mc];
    __shared__ float red[256];
    __shared__ float inv;
    int tid = threadIdx.x;
    if (tid < Mc) row[tid] = em[(size_t)be * Mc + tid];
    __syncthreads();
    float v0 = 0.f, v1 = 0.f;
    {
        const float* mb0 = mm + (size_t)b * Mc * Lc + tid;
        const float* mb1 = mm + (size_t)b * Mc * Lc + tid + 256;
        for (int m = 0; m < Mc; ++m) {
            v0 += row[m] * mb0[(size_t)m * Lc];
            v1 += row[m] * mb1[(size_t)m * Lc];
        }
    }
    red[tid] = v0 + v1;
    __syncthreads();
    for (int s = 128; s > 0; s >>= 1) { if (tid < s) red[tid] += red[tid + s]; __syncthreads(); }
    if (tid == 0) inv = 1.f / (red[0] + MINV);
    __syncthreads();
    emt[(size_t)be * Lc + tid] = v0 * inv;
    emt[(size_t)be * Lc + tid + 256] = v1 * inv;
}

// ---------------- K7 v3: ent_att via MFMA, m-tile 64, grid 384 ----------------
// eat[32e, m] = emt[32e, l] @ att[l, m]; waves = (m-half, kc-parity), LDS merge.
__global__ __launch_bounds__(256) void k_entatt3(const float* __restrict__ emt,
                                                 const float* __restrict__ att,
                                                 float* __restrict__ eat) {
    __shared__ __align__(16) bf16 emtS[32 * 64 * 8];   // 32 KB
    __shared__ __align__(16) bf16 attS[64 * 8 * 8];    // 8 KB
    __shared__ float mbuf[2][32 * 32];                 // 8 KB
    int id = blockIdx.x;
    int mt = id & 7; int bh = id >> 3;
    int b = bh / Hc, h = bh % Hc;
    int m0 = mt * 64;
    int tid = threadIdx.x;
    int w = tid >> 6, lane = tid & 63;
    int w_m = w & 1, w_k = w >> 1;
    int n_l = lane & 31, kg = lane >> 5;

    // stage emt (fp32 -> bf16), swizzled chunks (full 512 l)
    {
        int e = tid >> 3; int cbase = (tid & 7) * 8;
        const float* src = emt + (size_t)(b * Ec + e) * Lc;
#pragma unroll
        for (int j = 0; j < 8; ++j) {
            int cc = cbase + j;
            bf16x8 v;
#pragma unroll
            for (int jj = 0; jj < 8; ++jj) v[jj] = (bf16)src[cc * 8 + jj];
            ((bf16x8*)emtS)[e * 64 + (cc ^ (e & 7))] = v;
        }
    }
    f32x16 acc;
#pragma unroll
    for (int i = 0; i < 16; ++i) acc[i] = 0.f;

    const float* ab = att + (size_t)(b * Hc + h) * Lc * Lc + m0;
    int mRow = tid & 63; int lg = tid >> 6;   // lg: l-quarter (16 l each)
    float pre[16];
#pragma unroll
    for (int q = 0; q < 16; ++q) pre[q] = ab[(size_t)(lg * 16 + q) * Lc + mRow];

    int mr = w_m * 32 + n_l;
    for (int kc = 0; kc < 8; ++kc) {
        __syncthreads();
#pragma unroll
        for (int half = 0; half < 2; ++half) {
            int cc = lg * 2 + half;
            bf16x8 v;
#pragma unroll
            for (int jj = 0; jj < 8; ++jj) v[jj] = (bf16)pre[half * 8 + jj];
            ((bf16x8*)attS)[mRow * 8 + (cc ^ (mRow & 7))] = v;
        }
        if (kc < 7) {
#pragma unroll
            for (int q = 0; q < 16; ++q)
                pre[q] = ab[(size_t)((kc + 1) * 64 + lg * 16 + q) * Lc + mRow];
        }
        __syncthreads();
        if (w_k == (kc & 1)) {
#pragma unroll
            for (int s = 0; s < 4; ++s) {
                int ccA = kc * 8 + s * 2 + kg;
                bf16x8 a = ((const bf16x8*)emtS)[n_l * 64 + (ccA ^ (n_l & 7))];
                int ccB = s * 2 + kg;
                bf16x8 bb = ((const bf16x8*)attS)[mr * 8 + (ccB ^ (mr & 7))];
                acc = __builtin_amdgcn_mfma_f32_32x32x16_bf16(a, bb, acc, 0, 0, 0);
            }
        }
    }
    // merge kc-parity pairs
    __syncthreads();
    if (w_k == 1) {
#pragma unroll
        for (int reg = 0; reg < 16; ++reg) {
            int e = (reg & 3) + 8 * (reg >> 2) + 4 * kg;
            mbuf[w_m][e * 32 + n_l] = acc[reg];
        }
    }
    __syncthreads();
    if (w_k == 0) {
#pragma unroll
        for (int reg = 0; reg < 16; ++reg) {
            int e = (reg & 3) + 8 * (reg >> 2) + 4 * kg;
            float v = acc[reg] + mbuf[w_m][e * 32 + n_l];
            eat[((size_t)(b * Hc + h) * Ec + e) * Lc + m0 + w_m * 32 + n_l] = v;
        }
    }
}

// ---------------- K8: ctx_att[b,p,l] = sum_h eat[b,h,hi,l]*eat[b,h,ti,l], normalized ----------------
__global__ __launch_bounds__(256) void k_ctxatt(const int* __restrict__ hts,
                                                const float* __restrict__ eat,
                                                float* __restrict__ ca) {
    int bp = blockIdx.x; int b = bp / Pc;
    int hi = hts[bp * 2], ti = hts[bp * 2 + 1];
    int tid = threadIdx.x;
    float a0 = 0.f, a1 = 0.f;
    for (int h = 0; h < Hc; ++h) {
        const float* ph = eat + ((size_t)(b * Hc + h) * Ec + hi) * Lc;
        const float* pt = eat + ((size_t)(b * Hc + h) * Ec + ti) * Lc;
        a0 += ph[tid] * pt[tid];
        a1 += ph[tid + 256] * pt[tid + 256];
    }
    __shared__ float red[256];
    __shared__ float inv;
    red[tid] = a0 + a1;
    __syncthreads();
    for (int s = 128; s > 0; s >>= 1) { if (tid < s) red[tid] += red[tid + s]; __syncthreads(); }
    if (tid == 0) inv = 1.f / (red[0] + MINV);
    __syncthreads();
    ca[(size_t)bp * Lc + tid] = a0 * inv;
    ca[(size_t)bp * Lc + tid + 256] = a1 * inv;
}

// ---------------- K9 v2: context_info via MFMA: ci[p,d] = mask(p) * sum_l ca[p,l] ctxT[d,l] ----------------
__global__ __launch_bounds__(256) void k_ctxinfo_mfma(const int* __restrict__ hts,
                                                      const float* __restrict__ ca,
                                                      const bf16* __restrict__ ctxT,
                                                      bf16* __restrict__ ci) {
    __shared__ __align__(16) bf16 As[2][64 * 64];
    __shared__ __align__(16) bf16 Bs[2][64 * 64];
    __shared__ float maskS[64];
    int id = blockIdx.x;            // ((b*8+pt)*12+dt)
    int dt = id % 12; int pt = (id / 12) % 8; int b = id / 96;
    int p0 = pt * 64, d0 = dt * 64;
    int tid = threadIdx.x;
    int w = tid >> 6, lane = tid & 63;
    int w_m = w & 1, w_n = w >> 1;
    int m_l = lane & 31, kg = lane >> 5;
    int r0 = tid >> 3, cc0 = tid & 7;
    int r1 = r0 + 32;
    if (tid < 64) {
        int bp = b * Pc + p0 + tid;
        maskS[tid] = (hts[bp * 2] + hts[bp * 2 + 1] != 0) ? 1.f : 0.f;
    }
    bf16x8 ar0, ar1, br0, br1;
    auto loadt = [&](int it) {
        int k0 = it * 64;
        const float* A0 = ca + (size_t)(b * Pc + p0 + r0) * Lc + k0 + cc0 * 8;
        const float* A1 = ca + (size_t)(b * Pc + p0 + r1) * Lc + k0 + cc0 * 8;
        float4 x0 = *(const float4*)A0, x1 = *(const float4*)(A0 + 4);
        float4 y0 = *(const float4*)A1, y1 = *(const float4*)(A1 + 4);
        ar0[0] = (bf16)x0.x; ar0[1] = (bf16)x0.y; ar0[2] = (bf16)x0.z; ar0[3] = (bf16)x0.w;
        ar0[4] = (bf16)x1.x; ar0[5] = (bf16)x1.y; ar0[6] = (bf16)x1.z; ar0[7] = (bf16)x1.w;
        ar1[0] = (bf16)y0.x; ar1[1] = (bf16)y0.y; ar1[2] = (bf16)y0.z; ar1[3] = (bf16)y0.w;
        ar1[4] = (bf16)y1.x; ar1[5] = (bf16)y1.y; ar1[6] = (bf16)y1.z; ar1[7] = (bf16)y1.w;
        br0 = *(const bf16x8*)(ctxT + (size_t)(b * Dc + d0 + r0) * Lc + k0 + cc0 * 8);
        br1 = *(const bf16x8*)(ctxT + (size_t)(b * Dc + d0 + r1) * Lc + k0 + cc0 * 8);
    };
    auto writet = [&](int p) {
        ((bf16x8*)As[p])[r0 * 8 + (cc0 ^ (r0 & 7))] = ar0;
        ((bf16x8*)As[p])[r1 * 8 + (cc0 ^ (r1 & 7))] = ar1;
        ((bf16x8*)Bs[p])[r0 * 8 + (cc0 ^ (r0 & 7))] = br0;
        ((bf16x8*)Bs[p])[r1 * 8 + (cc0 ^ (r1 & 7))] = br1;
    };
    loadt(0);
    writet(0);
    loadt(1);
    f32x16 acc;
#pragma unroll
    for (int i = 0; i < 16; ++i) acc[i] = 0.f;
    int ar = w_m * 32 + m_l;
    int br = w_n * 32 + m_l;
    for (int it = 0; it < 8; ++it) {
        int p = it & 1;
        __syncthreads();
        if (it < 7) writet(p ^ 1);
        if (it < 6) loadt(it + 2);
#pragma unroll
        for (int s = 0; s < 4; ++s) {
            int ck = s * 2 + kg;
            bf16x8 a = ((const bf16x8*)As[p])[ar * 8 + (ck ^ (ar & 7))];
            bf16x8 bv = ((const bf16x8*)Bs[p])[br * 8 + (ck ^ (br & 7))];
            acc = __builtin_amdgcn_mfma_f32_32x32x16_bf16(a, bv, acc, 0, 0, 0);
        }
    }
#pragma unroll
    for (int reg = 0; reg < 16; ++reg) {
        int row = (reg & 3) + 8 * (reg >> 2) + 4 * kg;
        int p = p0 + w_m * 32 + row;
        int d = d0 + w_n * 32 + m_l;
        ci[(size_t)(b * Pc + p) * Dc + d] = (bf16)(acc[reg] * maskS[w_m * 32 + row]);
    }
}

// ---------------- K10: MFMA proj (1-barrier double-buffered) ----------------
__global__ __launch_bounds__(256) void k_proj_mfma(const bf16* __restrict__ X1, const bf16* __restrict__ W1,
                                                   const float* __restrict__ b1,
                                                   const bf16* __restrict__ X2, const bf16* __restrict__ W2,
                                                   const float* __restrict__ b2,
                                                   bf16* __restrict__ outp) {
    __shared__ __align__(16) bf16 Xs[2][64 * 64];
    __shared__ __align__(16) bf16 Ws[2][64 * 64];
    int m0 = blockIdx.x * 64, n0 = blockIdx.y * 64;
    int tid = threadIdx.x;
    int w = tid >> 6, lane = tid & 63;
    int w_m = w & 1, w_n = w >> 1;
    int m_l = lane & 31, kg = lane >> 5;
    const bf16* Xarr[2] = {X1, X2};
    const bf16* Warr[2] = {W1, W2};
    int r0 = tid >> 3, cc0 = tid & 7;
    int r1 = r0 + 32;
    bf16x8 xr0, xr1, wr0, wr1;
    auto loadt = [&](int it) {
        int src = it / 12; int k0 = (it % 12) * 64;
        const bf16* X = Xarr[src]; const bf16* W = Warr[src];
        xr0 = *(const bf16x8*)(X + (size_t)(m0 + r0) * Dc + k0 + cc0 * 8);
        xr1 = *(const bf16x8*)(X + (size_t)(m0 + r1) * Dc + k0 + cc0 * 8);
        wr0 = *(const bf16x8*)(W + (size_t)(n0 + r0) * Dc + k0 + cc0 * 8);
        wr1 = *(const bf16x8*)(W + (size_t)(n0 + r1) * Dc + k0 + cc0 * 8);
    };
    auto writet = [&](int p) {
        ((bf16x8*)Xs[p])[r0 * 8 + (cc0 ^ (r0 & 7))] = xr0;
        ((bf16x8*)Xs[p])[r1 * 8 + (cc0 ^ (r1 & 7))] = xr1;
        ((bf16x8*)Ws[p])[r0 * 8 + (cc0 ^ (r0 & 7))] = wr0;
        ((bf16x8*)Ws[p])[r1 * 8 + (cc0 ^ (r1 & 7))] = wr1;
    };
    loadt(0);
    writet(0);
    loadt(1);
    f32x16 acc;
#pragma unroll
    for (int i = 0; i < 16; ++i) acc[i] = 0.f;
    int ar = w_m * 32 + m_l;
    int br = w_n * 32 + m_l;
    for (int it = 0; it < 24; ++it) {
        int p = it & 1;
        __syncthreads();
        if (it < 23) writet(p ^ 1);
        if (it < 22) loadt(it + 2);
#pragma unroll
        for (int s = 0; s < 4; ++s) {
            int ck = s * 2 + kg;
            bf16x8 a = ((const bf16x8*)Xs[p])[ar * 8 + (ck ^ (ar & 7))];
            bf16x8 b = ((const bf16x8*)Ws[p])[br * 8 + (ck ^ (br & 7))];
            acc = __builtin_amdgcn_mfma_f32_32x32x16_bf16(a, b, acc, 0, 0, 0);
        }
    }
#pragma unroll
    for (int reg = 0; reg < 16; ++reg) {
        int row = (reg & 3) + 8 * (reg >> 2) + 4 * kg;
        int m = m0 + w_m * 32 + row;
        int n = n0 + w_n * 32 + m_l;
        float v = tanhf(acc[reg] + b1[n] + b2[n]);
        outp[(size_t)m * Dc + n] = (bf16)v;
    }
}

// ---------------- K11a: init out with bias ----------------
__global__ __launch_bounds__(256) void k_outinit(const float* __restrict__ cb, float* __restrict__ out) {
    int idx = blockIdx.x * 256 + threadIdx.x;
    if (idx < Bc * Pc * Rc) out[idx] = cb[idx % Rc];
}

// ---------------- K11b prep: swizzle clasW into MFMA-fragment layout ----------------
__global__ __launch_bounds__(256) void k_wprep(const float* __restrict__ W, bf16* __restrict__ Wp) {
    int gid = blockIdx.x * 256 + threadIdx.x;
    if (gid >= 768 * 16 * 64) return;
    int lane = gid & 63; int f = gid >> 6;
    int rt = f & 3; int s = (f >> 2) & 3; int c = f >> 4;
    int n_l = lane & 31, kg = lane >> 5;
    int r = rt * 32 + n_l;
    bf16x8 v;
    if (r < Rc) {
        const float* src = W + (size_t)r * (Dc * 64) + c * 64 + s * 16 + kg * 8;
#pragma unroll
        for (int j = 0; j < 8; ++j) v[j] = (bf16)src[j];
    } else {
#pragma unroll
        for (int j = 0; j < 8; ++j) v[j] = (bf16)0.f;
    }
    ((bf16x8*)Wp)[gid] = v;
}

// ---------------- K11b v3: group bilinear, whole-chunk B-frag register pipeline ----------------
__global__ __launch_bounds__(256, 2) void k_bilin3(const bf16* __restrict__ hF, const bf16* __restrict__ tF,
                                                   const bf16* __restrict__ Wp, float* __restrict__ outp) {
    __shared__ float smem[128 * 68 + 128 * 25];
    float* tS = smem;
    float* hS = smem + 128 * 68;
    float* mbuf = smem;
    int id = blockIdx.x;
    int tile = id >> 5;
    int slice = id & 31;
    int bp0 = tile * 128;
    int tid = threadIdx.x;
    int w = tid >> 6, lane = tid & 63;
    int w_m = w & 1, w_i = w >> 1;
    int m_l = lane & 31, kg = lane >> 5;
    int c0 = slice * 24, cEnd = c0 + 24;

    for (int idx = tid; idx < 128 * 24; idx += 256) {
        int bp = idx / 24, i = idx % 24;
        hS[bp * 25 + i] = (float)hF[(size_t)(bp0 + bp) * Dc + c0 + i];
    }

    f32x16 acc[2][4];
#pragma unroll
    for (int mt = 0; mt < 2; ++mt)
#pragma unroll
        for (int rt = 0; rt < 4; ++rt)
#pragma unroll
            for (int i = 0; i < 16; ++i) acc[mt][rt][i] = 0.f;

    int rowA = w_m * 64 + m_l;
    int rowB = rowA + 32;

    const bf16x8* WpB = (const bf16x8*)Wp;
    bf16x8 Bp[16];
    {
        int ccF = c0 + w_i;
#pragma unroll
        for (int f = 0; f < 16; ++f) Bp[f] = WpB[((size_t)ccF * 16 + f) * 64 + lane];
    }

    int c = c0;
    while (c < cEnd) {
        int n = c >> 6;
        int segEnd = (cEnd < (n + 1) * 64) ? cEnd : (n + 1) * 64;
        __syncthreads();
        for (int idx = tid; idx < 128 * 64; idx += 256) {
            int bp = idx >> 6, j = idx & 63;
            tS[bp * 68 + j] = (float)tF[(size_t)(bp0 + bp) * Dc + n * 64 + j];
        }
        __syncthreads();
        for (int cc = c + w_i; cc < segEnd; cc += 2) {
            int ii = cc - c0;
            float hv0 = hS[rowA * 25 + ii];
            float hv1 = hS[rowB * 25 + ii];
            int ccn = (cc + 2 < cEnd) ? cc + 2 : cc;
#pragma unroll
            for (int s = 0; s < 4; ++s) {
                const float* tp0 = &tS[rowA * 68 + s * 16 + kg * 8];
                const float* tp1 = &tS[rowB * 68 + s * 16 + kg * 8];
                bf16x8 a0, a1;
#pragma unroll
                for (int j = 0; j < 8; ++j) {
                    a0[j] = (bf16)(hv0 * tp0[j]);
                    a1[j] = (bf16)(hv1 * tp1[j]);
                }
                bf16x8 B0 = Bp[s * 4 + 0];
                bf16x8 B1 = Bp[s * 4 + 1];
                bf16x8 B2 = Bp[s * 4 + 2];
                bf16x8 B3 = Bp[s * 4 + 3];
                acc[0][0] = __builtin_amdgcn_mfma_f32_32x32x16_bf16(a0, B0, acc[0][0], 0, 0, 0);
                acc[1][0] = __builtin_amdgcn_mfma_f32_32x32x16_bf16(a1, B0, acc[1][0], 0, 0, 0);
                acc[0][1] = __builtin_amdgcn_mfma_f32_32x32x16_bf16(a0, B1, acc[0][1], 0, 0, 0);
                acc[1][1] = __builtin_amdgcn_mfma_f32_32x32x16_bf16(a1, B1, acc[1][1], 0, 0, 0);
                acc[0][2] = __builtin_amdgcn_mfma_f32_32x32x16_bf16(a0, B2, acc[0][2], 0, 0, 0);
                acc[1][2] = __builtin_amdgcn_mfma_f32_32x32x16_bf16(a1, B2, acc[1][2], 0, 0, 0);
                acc[0][3] = __builtin_amdgcn_mfma_f32_32x32x16_bf16(a0, B3, acc[0][3], 0, 0, 0);
                acc[1][3] = __builtin_amdgcn_mfma_f32_32x32x16_bf16(a1, B3, acc[1][3], 0, 0, 0);
                // prefetch next chunk's s-group into the regs just consumed
#pragma unroll
                for (int q = 0; q < 4; ++q)
                    Bp[s * 4 + q] = WpB[((size_t)ccn * 16 + s * 4 + q) * 64 + lane];
            }
        }
        c = segEnd;
    }

    for (int R = 0; R < 2; ++R) {
        __syncthreads();
        if (w_i == 1) {
#pragma unroll
            for (int mt = 0; mt < 2; ++mt)
#pragma unroll
                for (int q = 0; q < 2; ++q) {
                    int rt = R * 2 + q;
#pragma unroll
                    for (int reg = 0; reg < 16; ++reg) {
                        int row = (reg & 3) + 8 * (reg >> 2) + 4 * kg;
                        mbuf[(w_m * 64 + mt * 32 + row) * 64 + q * 32 + m_l] = acc[mt][rt][reg];
                    }
                }
        }
        __syncthreads();
        if (w_i == 0) {
#pragma unroll
            for (int mt = 0; mt < 2; ++mt)
#pragma unroll
                for (int q = 0; q < 2; ++q) {
                    int rt = R * 2 + q;
                    int r = rt * 32 + m_l;
                    if (r < Rc) {
#pragma unroll
                        for (int reg = 0; reg < 16; ++reg) {
                            int row = (reg & 3) + 8 * (reg >> 2) + 4 * kg;
                            int bp = bp0 + w_m * 64 + mt * 32 + row;
                            float v = acc[mt][rt][reg] + mbuf[(w_m * 64 + mt * 32 + row) * 64 + q * 32 + m_l];
                            atomicAdd(&outp[(size_t)bp * Rc + r], v);
                        }
                    }
                }
        }
    }
}

extern "C" void kernel_launch(void* const* d_in, const int* in_sizes, int n_in,
                              void* d_out, int out_size, void* d_ws, size_t ws_size,
                              hipStream_t stream) {
    const float* context   = (const float*)d_in[0];
    const float* attention = (const float*)d_in[1];
    const float* mm        = (const float*)d_in[2];
    const float* em        = (const float*)d_in[3];
    const int*   hts       = (const int*)d_in[4];
    const float* hW        = (const float*)d_in[5];
    const float* hb        = (const float*)d_in[6];
    const float* tW        = (const float*)d_in[7];
    const float* tb        = (const float*)d_in[8];
    const float* hcW       = (const float*)d_in[9];
    const float* hcb       = (const float*)d_in[10];
    const float* tcW       = (const float*)d_in[11];
    const float* tcb       = (const float*)d_in[12];
    const float* clasW     = (const float*)d_in[13];
    const float* clasb     = (const float*)d_in[14];
    float* out = (float*)d_out;

    char* wsb = (char*)d_ws;
    auto alloc = [&](size_t bytes) { char* p = wsb; wsb += (bytes + 255) & ~(size_t)255; return p; };
    float* mention     = (float*)alloc((size_t)Bc * Mc * Dc * 4);
    float* att_sum     = (float*)alloc((size_t)Bc * Lc * Lc * 4);
    float* tmpML       = (float*)alloc((size_t)Bc * Mc * Lc * 4);
    float* mention_att = (float*)alloc((size_t)Bc * Mc * Mc * 4);
    float* entity_att  = (float*)alloc((size_t)Bc * Ec * Mc * 4);
    float* em_tok      = (float*)alloc((size_t)Bc * Ec * Lc * 4);
    float* ent_att     = (float*)alloc((size_t)Bc * Hc * Ec * Lc * 4);
    float* ctx_att     = (float*)alloc((size_t)Bc * Pc * Lc * 4);
    bf16* h_buf   = (bf16*)alloc((size_t)Bc * Pc * Dc * 2);
    bf16* t_buf   = (bf16*)alloc((size_t)Bc * Pc * Dc * 2);
    bf16* ctxinfo = (bf16*)alloc((size_t)Bc * Pc * Dc * 2);
    bf16* h_fin   = (bf16*)alloc((size_t)Bc * Pc * Dc * 2);
    bf16* t_fin   = (bf16*)alloc((size_t)Bc * Pc * Dc * 2);
    bf16* hWb     = (bf16*)alloc((size_t)Dc * Dc * 2);
    bf16* tWb     = (bf16*)alloc((size_t)Dc * Dc * 2);
    bf16* hcWb    = (bf16*)alloc((size_t)Dc * Dc * 2);
    bf16* tcWb    = (bf16*)alloc((size_t)Dc * Dc * 2);
    bf16* ctxT    = (bf16*)alloc((size_t)Bc * Dc * Lc * 2);
    bf16* Wp      = (bf16*)alloc((size_t)768 * 16 * 64 * 8 * 2);

    k_cvt4<<<dim3(2048), dim3(256), 0, stream>>>(hW, tW, hcW, tcW, hWb, tWb, hcWb, tcWb);
    k_wprep<<<dim3(3072), dim3(256), 0, stream>>>(clasW, Wp);
    k_tran<<<dim3(384), dim3(256), 0, stream>>>(context, ctxT);

    k_attsum<<<dim3(1024), dim3(256), 0, stream>>>(attention, att_sum);
    k_mention<<<dim3(Bc * Mc * 3), dim3(256), 0, stream>>>(mm, context, mention);
    k_mm_attsum<<<dim3(Bc * Mc * 2), dim3(256), 0, stream>>>(mm, att_sum, tmpML);
    k_mention_att<<<dim3((Bc * Mc * Mc + 255) / 256), dim3(256), 0, stream>>>(tmpML, mm, mention_att);
    k_entity_att<<<dim3((Bc * Ec * Mc + 255) / 256), dim3(256), 0, stream>>>(em, mention_att, entity_att);
    k_ht<<<dim3(Bc * Pc), dim3(256), 0, stream>>>(hts, em, entity_att, mention, h_buf, t_buf);
    k_emtok<<<dim3(Bc * Ec), dim3(256), 0, stream>>>(em, mm, em_tok);
    k_entatt3<<<dim3(Bc * Hc * 8), dim3(256), 0, stream>>>(em_tok, attention, ent_att);
    k_ctxatt<<<dim3(Bc * Pc), dim3(256), 0, stream>>>(hts, ent_att, ctx_att);
    k_ctxinfo_mfma<<<dim3(384), dim3(256), 0, stream>>>(hts, ctx_att, ctxT, ctxinfo);
    k_proj_mfma<<<dim3(32, 12), dim3(256), 0, stream>>>(h_buf, hWb, hb, ctxinfo, hcWb, hcb, h_fin);
    k_proj_mfma<<<dim3(32, 12), dim3(256), 0, stream>>>(t_buf, tWb, tb, ctxinfo, tcWb, tcb, t_fin);
    k_outinit<<<dim3((Bc * Pc * Rc + 255) / 256), dim3(256), 0, stream>>>(clasb, out);
    k_bilin3<<<dim3(512), dim3(256), 0, stream>>>(h_fin, t_fin, Wp, out);
}